// Round 1
// baseline (2203.893 us; speedup 1.0000x reference)
//
#include <hip/hip_runtime.h>
#include <math.h>

#define Timg 131072            // 8 * 128 * 128 tokens after merge
#define SCALE 0.17677669529663689f

// ---------------------------------------------------------------- K1: patch merge + GEMM (K=256 -> N=128)
__global__ __launch_bounds__(256) void k_patchmerge(
    const float* __restrict__ x, const float* __restrict__ Wm,
    const float* __restrict__ bm, float* __restrict__ t)
{
    __shared__ float A[32][256];
    int blk = blockIdx.x;          // T/32 = 4096 blocks; 32 tokens (b,h, w0..w0+31)
    int b   = blk >> 9;
    int rem = blk & 511;
    int h   = rem >> 2;
    int w0  = (rem & 3) << 5;
    int tid = threadIdx.x;
    {
        int row = tid >> 1, half = tid & 1;   // row = c*2+ki (128 rows), half selects 32 floats
        int c = row >> 1, ki = row & 1;
        const float* src = x + (((size_t)(b*64 + c))*256 + (size_t)(2*h + ki))*256 + 2*w0 + half*32;
        int base = c*4 + ki*2;                // k index = c*4 + ki*2 + kj
        #pragma unroll
        for (int q = 0; q < 8; ++q) {
            float4 v = *reinterpret_cast<const float4*>(src + q*4);
            int j0 = half*32 + q*4;           // j covers (w', kj): w' = j>>1, kj = j&1
            A[(j0>>1)    ][base  ] = v.x;
            A[(j0>>1)    ][base+1] = v.y;
            A[(j0>>1) + 1][base  ] = v.z;
            A[(j0>>1) + 1][base+1] = v.w;
        }
    }
    __syncthreads();
    int ng = tid & 31, tg = tid >> 5;         // 32 col-groups x 8 token-groups
    float acc[4][4] = {};
    for (int k = 0; k < 256; k += 4) {
        float wb[4][4];
        #pragma unroll
        for (int kk = 0; kk < 4; ++kk) {
            float4 wv = *reinterpret_cast<const float4*>(Wm + (size_t)(k+kk)*128 + ng*4);
            wb[kk][0]=wv.x; wb[kk][1]=wv.y; wb[kk][2]=wv.z; wb[kk][3]=wv.w;
        }
        #pragma unroll
        for (int m = 0; m < 4; ++m) {
            float4 av = *reinterpret_cast<const float4*>(&A[tg + m*8][k]);
            float a0=av.x, a1=av.y, a2=av.z, a3=av.w;
            #pragma unroll
            for (int nn = 0; nn < 4; ++nn)
                acc[m][nn] += a0*wb[0][nn] + a1*wb[1][nn] + a2*wb[2][nn] + a3*wb[3][nn];
        }
    }
    size_t tok0 = (size_t)blk * 32;
    #pragma unroll
    for (int m = 0; m < 4; ++m) {
        float4 o;
        o.x = acc[m][0] + bm[ng*4+0];
        o.y = acc[m][1] + bm[ng*4+1];
        o.z = acc[m][2] + bm[ng*4+2];
        o.w = acc[m][3] + bm[ng*4+3];
        *reinterpret_cast<float4*>(t + (tok0 + tg + m*8)*128 + ng*4) = o;
    }
}

// ---------------------------------------------------------------- K2: LayerNorm (C=128), one wave per token
__global__ __launch_bounds__(256) void k_ln(
    const float* __restrict__ t, const float* __restrict__ g,
    const float* __restrict__ bta, float* __restrict__ u)
{
    int lane = threadIdx.x & 63, wv = threadIdx.x >> 6;
    size_t token = (size_t)blockIdx.x*4 + wv;
    const float* p = t + token*128;
    float2 v = *reinterpret_cast<const float2*>(p + lane*2);
    float s = v.x + v.y;
    #pragma unroll
    for (int o = 32; o; o >>= 1) s += __shfl_xor(s, o);
    float mean = s * 0.0078125f;
    float d0 = v.x - mean, d1 = v.y - mean;
    float q = d0*d0 + d1*d1;
    #pragma unroll
    for (int o = 32; o; o >>= 1) q += __shfl_xor(q, o);
    float rs = rsqrtf(q * 0.0078125f + 1e-5f);
    float2 ov;
    ov.x = d0*rs*g[lane*2  ] + bta[lane*2  ];
    ov.y = d1*rs*g[lane*2+1] + bta[lane*2+1];
    *reinterpret_cast<float2*>(u + token*128 + lane*2) = ov;
}

// ---------------------------------------------------------------- generic GEMM: out[T x N] = A[T x K] @ W[K x N] (+bias) (+residual into out)
template<int KDIM, int NJ, bool HASBIAS, bool RESID>
__global__ __launch_bounds__(256) void k_gemm(
    const float* __restrict__ A_g, const float* __restrict__ Wt,
    const float* __restrict__ bias, float* __restrict__ out)
{
    constexpr int N = NJ*32;
    __shared__ float A[32][KDIM];
    size_t tok0 = (size_t)blockIdx.x * 32;
    int tid = threadIdx.x;
    constexpr int NLOOP = (32*KDIM/4)/256;
    #pragma unroll
    for (int q = 0; q < NLOOP; ++q) {
        int idx = tid + q*256;
        int m = idx / (KDIM/4), kq = idx % (KDIM/4);
        *reinterpret_cast<float4*>(&A[m][kq*4]) =
            *reinterpret_cast<const float4*>(A_g + (tok0+m)*KDIM + kq*4);
    }
    __syncthreads();
    int n = tid & 31, mg = tid >> 5;
    float acc[4][NJ] = {};
    for (int k = 0; k < KDIM; k += 4) {
        float a[4][4];
        #pragma unroll
        for (int m = 0; m < 4; ++m) {
            float4 av = *reinterpret_cast<const float4*>(&A[mg + m*8][k]);
            a[m][0]=av.x; a[m][1]=av.y; a[m][2]=av.z; a[m][3]=av.w;
        }
        #pragma unroll
        for (int kk = 0; kk < 4; ++kk) {
            float w[NJ];
            #pragma unroll
            for (int j = 0; j < NJ; ++j)
                w[j] = Wt[(size_t)(k+kk)*N + n + 32*j];
            #pragma unroll
            for (int m = 0; m < 4; ++m)
                #pragma unroll
                for (int j = 0; j < NJ; ++j)
                    acc[m][j] += a[m][kk] * w[j];
        }
    }
    #pragma unroll
    for (int m = 0; m < 4; ++m) {
        size_t rowo = (tok0 + mg + m*8) * (size_t)N;
        #pragma unroll
        for (int j = 0; j < NJ; ++j) {
            float val = acc[m][j];
            if (HASBIAS) val += bias[n + 32*j];
            if (RESID)   val += out[rowo + n + 32*j];
            out[rowo + n + 32*j] = val;
        }
    }
}

// ---------------------------------------------------------------- K4: window attention, one wave per (b, head, window)
__global__ __launch_bounds__(64) void k_attn(
    const float* __restrict__ qkv, const float* __restrict__ pos,
    float* __restrict__ ao, int shifted)
{
    __shared__ float Ks[64][36];
    __shared__ float Vs[64][36];
    __shared__ float ps[240];
    int blk  = blockIdx.x;          // 8*3*256 = 6144
    int win  = blk & 255;
    int bh   = blk >> 8;
    int head = bh % 3, b = bh / 3;
    int wy = win >> 4, wx = win & 15;
    int lane = threadIdx.x;
    int ir = lane >> 3, ic = lane & 7;
    int hh = wy*8 + ir, ww = wx*8 + ic;     // coords on (possibly rolled) grid
    if (shifted) { hh = (hh + 4) & 127; ww = (ww + 4) & 127; }  // rolled[h] = x[(h+4)%128]
    size_t tok = ((size_t)(b*128 + hh))*128 + ww;
    const float* base = qkv + tok*288 + head*32;  // layout (3, heads, hd)
    float qr[32];
    #pragma unroll
    for (int d4 = 0; d4 < 8; ++d4) {
        float4 qv = *reinterpret_cast<const float4*>(base + d4*4);
        qr[d4*4+0]=qv.x*SCALE; qr[d4*4+1]=qv.y*SCALE; qr[d4*4+2]=qv.z*SCALE; qr[d4*4+3]=qv.w*SCALE;
        *reinterpret_cast<float4*>(&Ks[lane][d4*4]) = *reinterpret_cast<const float4*>(base +  96 + d4*4);
        *reinterpret_cast<float4*>(&Vs[lane][d4*4]) = *reinterpret_cast<const float4*>(base + 192 + d4*4);
    }
    for (int idx = lane; idx < 225; idx += 64) ps[idx] = pos[idx];
    __syncthreads();

    bool mUL = (shifted != 0) && (wy == 15);   // window row 15: upper/lower mask
    bool mLR = (shifted != 0) && (wx == 15);   // window col 15: left/right mask
    bool ru = ir >= 4, rl = ic >= 4;
    int off = (7 - ir)*15 + (7 - ic);          // bias = pos[jr-ir+7][jc-ic+7]

    float s[64];
    float mx = -1e30f;
    #pragma unroll
    for (int j = 0; j < 64; ++j) {
        float acc = 0.f;
        #pragma unroll
        for (int d4 = 0; d4 < 8; ++d4) {
            float4 kv = *reinterpret_cast<const float4*>(&Ks[j][d4*4]);
            acc += qr[d4*4+0]*kv.x + qr[d4*4+1]*kv.y + qr[d4*4+2]*kv.z + qr[d4*4+3]*kv.w;
        }
        int jr = j >> 3, jc = j & 7;
        float val = acc + ps[off + jr*15 + jc];
        if ((mUL && ((jr>=4) != ru)) || (mLR && ((jc>=4) != rl))) val = -1e30f;
        s[j] = val;
        mx = fmaxf(mx, val);
    }
    float sum = 0.f;
    #pragma unroll
    for (int j = 0; j < 64; ++j) { float e = __expf(s[j] - mx); s[j] = e; sum += e; }
    float inv = 1.0f / sum;
    float o[32] = {};
    #pragma unroll
    for (int j = 0; j < 64; ++j) {
        float a = s[j] * inv;
        #pragma unroll
        for (int d4 = 0; d4 < 8; ++d4) {
            float4 vv = *reinterpret_cast<const float4*>(&Vs[j][d4*4]);
            o[d4*4+0] += a*vv.x; o[d4*4+1] += a*vv.y; o[d4*4+2] += a*vv.z; o[d4*4+3] += a*vv.w;
        }
    }
    float* dst = ao + tok*96 + head*32;   // scatter back to source token: undoes the roll
    #pragma unroll
    for (int d4 = 0; d4 < 8; ++d4) {
        float4 ov; ov.x=o[d4*4]; ov.y=o[d4*4+1]; ov.z=o[d4*4+2]; ov.w=o[d4*4+3];
        *reinterpret_cast<float4*>(dst + d4*4) = ov;
    }
}

// ---------------------------------------------------------------- K6: fused LN2 + MLP (128->512 gelu ->128) + residual, hidden chunked through LDS
__global__ __launch_bounds__(256) void k_mlp(
    float* __restrict__ t, const float* __restrict__ g, const float* __restrict__ be,
    const float* __restrict__ W1, const float* __restrict__ bf1,
    const float* __restrict__ W2, const float* __restrict__ bf2)
{
    __shared__ float A [32][128];
    __shared__ float Hd[32][128];
    size_t tok0 = (size_t)blockIdx.x * 32;
    int tid = threadIdx.x, lane = tid & 63, wv = tid >> 6;
    #pragma unroll
    for (int it = 0; it < 8; ++it) {
        int m = wv*8 + it;
        const float* p = t + (tok0 + m)*128;
        float2 v = *reinterpret_cast<const float2*>(p + lane*2);
        float s = v.x + v.y;
        #pragma unroll
        for (int o = 32; o; o >>= 1) s += __shfl_xor(s, o);
        float mean = s * 0.0078125f;
        float d0 = v.x - mean, d1 = v.y - mean;
        float q = d0*d0 + d1*d1;
        #pragma unroll
        for (int o = 32; o; o >>= 1) q += __shfl_xor(q, o);
        float rs = rsqrtf(q*0.0078125f + 1e-5f);
        A[m][lane*2  ] = d0*rs*g[lane*2  ] + be[lane*2  ];
        A[m][lane*2+1] = d1*rs*g[lane*2+1] + be[lane*2+1];
    }
    __syncthreads();
    int n = tid & 31, mg = tid >> 5;
    float acc2[4][4] = {};
    for (int kc = 0; kc < 4; ++kc) {         // 4 hidden chunks of 128
        float acc1[4][4] = {};
        for (int k = 0; k < 128; k += 4) {
            float a[4][4];
            #pragma unroll
            for (int m = 0; m < 4; ++m) {
                float4 av = *reinterpret_cast<const float4*>(&A[mg + m*8][k]);
                a[m][0]=av.x; a[m][1]=av.y; a[m][2]=av.z; a[m][3]=av.w;
            }
            #pragma unroll
            for (int kk = 0; kk < 4; ++kk) {
                float w[4];
                #pragma unroll
                for (int j = 0; j < 4; ++j)
                    w[j] = W1[(size_t)(k+kk)*512 + kc*128 + n + 32*j];
                #pragma unroll
                for (int m = 0; m < 4; ++m)
                    #pragma unroll
                    for (int j = 0; j < 4; ++j)
                        acc1[m][j] += a[m][kk] * w[j];
            }
        }
        __syncthreads();   // prev chunk's gemm2 done reading Hd
        #pragma unroll
        for (int m = 0; m < 4; ++m)
            #pragma unroll
            for (int j = 0; j < 4; ++j) {
                float xv = acc1[m][j] + bf1[kc*128 + n + 32*j];
                Hd[mg + m*8][n + 32*j] = 0.5f*xv*(1.f + erff(xv*0.70710678118f));
            }
        __syncthreads();
        for (int k = 0; k < 128; k += 4) {
            float hb[4][4];
            #pragma unroll
            for (int m = 0; m < 4; ++m) {
                float4 hv = *reinterpret_cast<const float4*>(&Hd[mg + m*8][k]);
                hb[m][0]=hv.x; hb[m][1]=hv.y; hb[m][2]=hv.z; hb[m][3]=hv.w;
            }
            #pragma unroll
            for (int kk = 0; kk < 4; ++kk) {
                float w[4];
                #pragma unroll
                for (int j = 0; j < 4; ++j)
                    w[j] = W2[(size_t)(kc*128 + k + kk)*128 + n + 32*j];
                #pragma unroll
                for (int m = 0; m < 4; ++m)
                    #pragma unroll
                    for (int j = 0; j < 4; ++j)
                        acc2[m][j] += hb[m][kk] * w[j];
            }
        }
    }
    #pragma unroll
    for (int m = 0; m < 4; ++m) {
        size_t row = (tok0 + mg + m*8)*128;
        #pragma unroll
        for (int j = 0; j < 4; ++j) {
            int col = n + 32*j;
            t[row + col] = t[row + col] + acc2[m][j] + bf2[col];
        }
    }
}

// ---------------------------------------------------------------- K7: NHWC -> NCHW transpose
__global__ __launch_bounds__(256) void k_transpose(
    const float* __restrict__ t, float* __restrict__ out)
{
    __shared__ float tile[128][33];
    int blk = blockIdx.x;                 // 8 * 128 * 4
    int ct = blk & 3;
    int h  = (blk >> 2) & 127;
    int b  = blk >> 9;
    const float* src = t + ((size_t)b*16384 + (size_t)h*128)*128 + ct*32;
    #pragma unroll
    for (int q = 0; q < 16; ++q) {
        int idx = threadIdx.x + q*256;
        int w = idx >> 5, c = idx & 31;
        tile[w][c] = src[(size_t)w*128 + c];
    }
    __syncthreads();
    float* dst = out + ((size_t)(b*128 + ct*32))*16384 + (size_t)h*128;
    #pragma unroll
    for (int q = 0; q < 16; ++q) {
        int idx = threadIdx.x + q*256;
        int c = idx >> 7, w = idx & 127;
        dst[(size_t)c*16384 + w] = tile[w][c];
    }
}

// ----------------------------------------------------------------
extern "C" void kernel_launch(void* const* d_in, const int* in_sizes, int n_in,
                              void* d_out, int out_size, void* d_ws, size_t ws_size,
                              hipStream_t stream)
{
    const float* x  = (const float*)d_in[0];
    const float* Wm = (const float*)d_in[1];
    const float* bm = (const float*)d_in[2];

    float* t   = (float*)d_ws;                       //  T x 128  (64 MB)
    float* qkv = t   + (size_t)Timg*128;             //  T x 288  (144 MB)
    float* ao  = qkv + (size_t)Timg*288;             //  T x 96   (48 MB)
    float* u   = (float*)d_out;                      //  LN scratch; overwritten by final transpose

    k_patchmerge<<<Timg/32, 256, 0, stream>>>(x, Wm, bm, t);

    for (int blk = 0; blk < 2; ++blk) {
        const float* g1   = (const float*)d_in[ 3 + blk*12];
        const float* b1   = (const float*)d_in[ 4 + blk*12];
        const float* Wqkv = (const float*)d_in[ 5 + blk*12];
        const float* pos  = (const float*)d_in[ 6 + blk*12];
        const float* Wo   = (const float*)d_in[ 7 + blk*12];
        const float* bo   = (const float*)d_in[ 8 + blk*12];
        const float* g2   = (const float*)d_in[ 9 + blk*12];
        const float* b2   = (const float*)d_in[10 + blk*12];
        const float* W1   = (const float*)d_in[11 + blk*12];
        const float* bf1  = (const float*)d_in[12 + blk*12];
        const float* W2   = (const float*)d_in[13 + blk*12];
        const float* bf2  = (const float*)d_in[14 + blk*12];

        k_ln<<<Timg/4, 256, 0, stream>>>(t, g1, b1, u);
        k_gemm<128, 9, false, false><<<Timg/32, 256, 0, stream>>>(u, Wqkv, nullptr, qkv);
        k_attn<<<8*3*256, 64, 0, stream>>>(qkv, pos, ao, blk);
        k_gemm<96, 4, true, true><<<Timg/32, 256, 0, stream>>>(ao, Wo, bo, t);
        k_mlp<<<Timg/32, 256, 0, stream>>>(t, g2, b2, W1, bf1, W2, bf2);
    }

    k_transpose<<<8*128*4, 256, 0, stream>>>(t, (float*)d_out);
}

// Round 2
// 1022.027 us; speedup vs baseline: 2.1564x; 2.1564x over previous
//
#include <hip/hip_runtime.h>
#include <math.h>

#define Timg 131072            // 8 * 128 * 128 tokens after merge
#define SCALE 0.17677669529663689f

typedef __attribute__((ext_vector_type(8))) short frag8;
typedef __attribute__((ext_vector_type(8))) unsigned short us8;
typedef __attribute__((ext_vector_type(4))) float f32x4;

__device__ inline float bf2f(unsigned short u) {
    union { unsigned int i; float f; } v; v.i = ((unsigned int)u) << 16; return v.f;
}
__device__ inline unsigned short f2bf(float f) {
    union { float f; unsigned int i; } v; v.f = f;
    unsigned int r = v.i + 0x7fff + ((v.i >> 16) & 1);
    return (unsigned short)(r >> 16);
}

// ---------------------------------------------------------------- weight convert+transpose: dst[c][r] = bf16(src[r][c])
__global__ __launch_bounds__(256) void k_wcvt(
    const float* __restrict__ src, unsigned short* __restrict__ dst, int R, int C)
{
    int idx = blockIdx.x * 256 + threadIdx.x;
    if (idx >= R * C) return;
    int r = idx / C, c = idx % C;
    dst[(size_t)c * R + r] = f2bf(src[idx]);
}

// ---------------------------------------------------------------- K1: patch merge + MFMA GEMM (K=256 -> N=128)
#define LDA_PM 264  // 256+8 bf16, row stride 528B -> 2-way banks (free)
__global__ __launch_bounds__(256) void k_patchmerge(
    const float* __restrict__ x, const unsigned short* __restrict__ Wmt,
    const float* __restrict__ bm, float* __restrict__ t)
{
    __shared__ unsigned short A[32 * LDA_PM];
    int blk = blockIdx.x;          // 4096 blocks; 32 tokens (b,h, w0..w0+31)
    int b   = blk >> 9;
    int rem = blk & 511;
    int h   = rem >> 2;
    int w0  = (rem & 3) << 5;
    int tid = threadIdx.x;
    {
        int row = tid >> 1, half = tid & 1;   // row = c*2+ki
        int c = row >> 1, ki = row & 1;
        const float* src = x + (((size_t)(b*64 + c))*256 + (size_t)(2*h + ki))*256 + 2*w0 + half*32;
        int base = c*4 + ki*2;                // k index = c*4 + ki*2 + kj
        #pragma unroll
        for (int q = 0; q < 8; ++q) {
            float4 v = *reinterpret_cast<const float4*>(src + q*4);
            int tk0 = (half*32 + q*4) >> 1;
            A[ tk0     * LDA_PM + base    ] = f2bf(v.x);
            A[ tk0     * LDA_PM + base + 1] = f2bf(v.y);
            A[(tk0 + 1)* LDA_PM + base    ] = f2bf(v.z);
            A[(tk0 + 1)* LDA_PM + base + 1] = f2bf(v.w);
        }
    }
    __syncthreads();
    int lane = tid & 63, w = tid >> 6;
    int lr = lane & 15, lg = lane >> 4;
    int mrow = (w >> 1) * 16, nhalf = (w & 1) * 64;
    frag8 a[8];
    #pragma unroll
    for (int ks = 0; ks < 8; ++ks)
        a[ks] = *reinterpret_cast<const frag8*>(&A[(mrow + lr)*LDA_PM + ks*32 + lg*8]);
    size_t tok0 = (size_t)blk * 32;
    #pragma unroll
    for (int nt = 0; nt < 4; ++nt) {
        int n0 = nhalf + nt*16;
        const unsigned short* bp = Wmt + (size_t)(n0 + lr)*256 + lg*8;
        f32x4 acc = {0.f, 0.f, 0.f, 0.f};
        #pragma unroll
        for (int ks = 0; ks < 8; ++ks)
            acc = __builtin_amdgcn_mfma_f32_16x16x32_bf16(a[ks],
                      *reinterpret_cast<const frag8*>(bp + ks*32), acc, 0, 0, 0);
        #pragma unroll
        for (int r = 0; r < 4; ++r) {
            int rowl = mrow + lg*4 + r;
            int col  = n0 + lr;
            t[(tok0 + rowl)*128 + col] = acc[r] + bm[col];
        }
    }
}

// ---------------------------------------------------------------- K2: fused LN1 + QKV GEMM (128 -> 288), bf16 out
#define LDA_Q 136
__global__ __launch_bounds__(256) void k_qkv(
    const float* __restrict__ t, const float* __restrict__ g, const float* __restrict__ be,
    const unsigned short* __restrict__ Wqt, unsigned short* __restrict__ qkv)
{
    __shared__ unsigned short A[32 * LDA_Q];
    size_t tok0 = (size_t)blockIdx.x * 32;
    int tid = threadIdx.x, lane = tid & 63, w = tid >> 6;
    #pragma unroll
    for (int it = 0; it < 8; ++it) {
        int m = w*8 + it;
        const float* p = t + (tok0 + m)*128;
        float2 v = *reinterpret_cast<const float2*>(p + lane*2);
        float s = v.x + v.y;
        #pragma unroll
        for (int o = 32; o; o >>= 1) s += __shfl_xor(s, o);
        float mean = s * 0.0078125f;
        float d0 = v.x - mean, d1 = v.y - mean;
        float q = d0*d0 + d1*d1;
        #pragma unroll
        for (int o = 32; o; o >>= 1) q += __shfl_xor(q, o);
        float rs = rsqrtf(q * 0.0078125f + 1e-5f);
        A[m*LDA_Q + lane*2    ] = f2bf(d0*rs*g[lane*2    ] + be[lane*2    ]);
        A[m*LDA_Q + lane*2 + 1] = f2bf(d1*rs*g[lane*2 + 1] + be[lane*2 + 1]);
    }
    __syncthreads();
    int lr = lane & 15, lg = lane >> 4;
    int mrow = (w >> 1)*16, nbase = (w & 1)*144;
    frag8 a[4];
    #pragma unroll
    for (int ks = 0; ks < 4; ++ks)
        a[ks] = *reinterpret_cast<const frag8*>(&A[(mrow + lr)*LDA_Q + ks*32 + lg*8]);
    #pragma unroll
    for (int nt = 0; nt < 9; ++nt) {
        int n0 = nbase + nt*16;
        const unsigned short* bp = Wqt + (size_t)(n0 + lr)*128 + lg*8;
        f32x4 acc = {0.f, 0.f, 0.f, 0.f};
        #pragma unroll
        for (int ks = 0; ks < 4; ++ks)
            acc = __builtin_amdgcn_mfma_f32_16x16x32_bf16(a[ks],
                      *reinterpret_cast<const frag8*>(bp + ks*32), acc, 0, 0, 0);
        #pragma unroll
        for (int r = 0; r < 4; ++r) {
            int rowl = mrow + lg*4 + r;
            qkv[(tok0 + rowl)*288 + n0 + lr] = f2bf(acc[r]);
        }
    }
}

// ---------------------------------------------------------------- K4: window attention, one wave per (b, head, window)
__global__ __launch_bounds__(64) void k_attn(
    const unsigned short* __restrict__ qkv, const float* __restrict__ pos,
    unsigned short* __restrict__ ao, int shifted)
{
    __shared__ float Ks[64][36];
    __shared__ float Vs[64][36];
    __shared__ float ps[240];
    int blk  = blockIdx.x;          // 8*3*256 = 6144
    int win  = blk & 255;
    int bh   = blk >> 8;
    int head = bh % 3, b = bh / 3;
    int wy = win >> 4, wx = win & 15;
    int lane = threadIdx.x;
    int ir = lane >> 3, ic = lane & 7;
    int hh = wy*8 + ir, ww = wx*8 + ic;
    if (shifted) { hh = (hh + 4) & 127; ww = (ww + 4) & 127; }
    size_t tok = ((size_t)(b*128 + hh))*128 + ww;
    const unsigned short* base = qkv + tok*288 + head*32;
    float qr[32];
    #pragma unroll
    for (int d8 = 0; d8 < 4; ++d8) {
        us8 qv = *reinterpret_cast<const us8*>(base + d8*8);
        us8 kv = *reinterpret_cast<const us8*>(base +  96 + d8*8);
        us8 vv = *reinterpret_cast<const us8*>(base + 192 + d8*8);
        #pragma unroll
        for (int j = 0; j < 8; ++j) {
            qr[d8*8 + j]       = bf2f(qv[j]) * SCALE;
            Ks[lane][d8*8 + j] = bf2f(kv[j]);
            Vs[lane][d8*8 + j] = bf2f(vv[j]);
        }
    }
    for (int idx = lane; idx < 225; idx += 64) ps[idx] = pos[idx];
    __syncthreads();

    bool mUL = (shifted != 0) && (wy == 15);
    bool mLR = (shifted != 0) && (wx == 15);
    bool ru = ir >= 4, rl = ic >= 4;
    int off = (7 - ir)*15 + (7 - ic);

    float s[64];
    float mx = -1e30f;
    #pragma unroll
    for (int j = 0; j < 64; ++j) {
        float acc = 0.f;
        #pragma unroll
        for (int d4 = 0; d4 < 8; ++d4) {
            float4 kv = *reinterpret_cast<const float4*>(&Ks[j][d4*4]);
            acc += qr[d4*4+0]*kv.x + qr[d4*4+1]*kv.y + qr[d4*4+2]*kv.z + qr[d4*4+3]*kv.w;
        }
        int jr = j >> 3, jc = j & 7;
        float val = acc + ps[off + jr*15 + jc];
        if ((mUL && ((jr>=4) != ru)) || (mLR && ((jc>=4) != rl))) val = -1e30f;
        s[j] = val;
        mx = fmaxf(mx, val);
    }
    float sum = 0.f;
    #pragma unroll
    for (int j = 0; j < 64; ++j) { float e = __expf(s[j] - mx); s[j] = e; sum += e; }
    float inv = 1.0f / sum;
    float o[32] = {};
    #pragma unroll
    for (int j = 0; j < 64; ++j) {
        float a = s[j] * inv;
        #pragma unroll
        for (int d4 = 0; d4 < 8; ++d4) {
            float4 vv = *reinterpret_cast<const float4*>(&Vs[j][d4*4]);
            o[d4*4+0] += a*vv.x; o[d4*4+1] += a*vv.y; o[d4*4+2] += a*vv.z; o[d4*4+3] += a*vv.w;
        }
    }
    unsigned short* dst = ao + tok*96 + head*32;
    #pragma unroll
    for (int d8 = 0; d8 < 4; ++d8) {
        us8 ov;
        #pragma unroll
        for (int j = 0; j < 8; ++j) ov[j] = f2bf(o[d8*8 + j]);
        *reinterpret_cast<us8*>(dst + d8*8) = ov;
    }
}

// ---------------------------------------------------------------- K5: proj GEMM (96 -> 128) + residual into t
__global__ __launch_bounds__(256) void k_proj(
    const unsigned short* __restrict__ ao, const unsigned short* __restrict__ Wot,
    const float* __restrict__ bo, float* __restrict__ t)
{
    size_t tok0 = (size_t)blockIdx.x * 32;
    int tid = threadIdx.x, lane = tid & 63, w = tid >> 6;
    int lr = lane & 15, lg = lane >> 4;
    int mrow = (w >> 1)*16, nhalf = (w & 1)*64;
    frag8 a[3];
    const unsigned short* ap = ao + (tok0 + mrow + lr)*96 + lg*8;
    #pragma unroll
    for (int ks = 0; ks < 3; ++ks) a[ks] = *reinterpret_cast<const frag8*>(ap + ks*32);
    #pragma unroll
    for (int nt = 0; nt < 4; ++nt) {
        int n0 = nhalf + nt*16;
        const unsigned short* bp = Wot + (size_t)(n0 + lr)*96 + lg*8;
        f32x4 acc = {0.f, 0.f, 0.f, 0.f};
        #pragma unroll
        for (int ks = 0; ks < 3; ++ks)
            acc = __builtin_amdgcn_mfma_f32_16x16x32_bf16(a[ks],
                      *reinterpret_cast<const frag8*>(bp + ks*32), acc, 0, 0, 0);
        #pragma unroll
        for (int r = 0; r < 4; ++r) {
            int rowl = mrow + lg*4 + r;
            int col  = n0 + lr;
            size_t off = (tok0 + rowl)*128 + col;
            t[off] += acc[r] + bo[col];
        }
    }
}

// ---------------------------------------------------------------- K6: fused LN2 + MLP (128->512 gelu ->128) + residual
#define LDA_M 136
#define LDH_M 520
__global__ __launch_bounds__(256) void k_mlp(
    float* __restrict__ t, const float* __restrict__ g, const float* __restrict__ be,
    const unsigned short* __restrict__ W1t, const float* __restrict__ bf1,
    const unsigned short* __restrict__ W2t, const float* __restrict__ bf2)
{
    __shared__ unsigned short A[32 * LDA_M];
    __shared__ unsigned short H[32 * LDH_M];
    size_t tok0 = (size_t)blockIdx.x * 32;
    int tid = threadIdx.x, lane = tid & 63, w = tid >> 6;
    #pragma unroll
    for (int it = 0; it < 8; ++it) {
        int m = w*8 + it;
        const float* p = t + (tok0 + m)*128;
        float2 v = *reinterpret_cast<const float2*>(p + lane*2);
        float s = v.x + v.y;
        #pragma unroll
        for (int o = 32; o; o >>= 1) s += __shfl_xor(s, o);
        float mean = s * 0.0078125f;
        float d0 = v.x - mean, d1 = v.y - mean;
        float q = d0*d0 + d1*d1;
        #pragma unroll
        for (int o = 32; o; o >>= 1) q += __shfl_xor(q, o);
        float rs = rsqrtf(q*0.0078125f + 1e-5f);
        A[m*LDA_M + lane*2    ] = f2bf(d0*rs*g[lane*2    ] + be[lane*2    ]);
        A[m*LDA_M + lane*2 + 1] = f2bf(d1*rs*g[lane*2 + 1] + be[lane*2 + 1]);
    }
    __syncthreads();
    int lr = lane & 15, lg = lane >> 4;
    int mrow = (w >> 1)*16, nhalf = (w & 1)*256;
    frag8 a[4];
    #pragma unroll
    for (int ks = 0; ks < 4; ++ks)
        a[ks] = *reinterpret_cast<const frag8*>(&A[(mrow + lr)*LDA_M + ks*32 + lg*8]);
    #pragma unroll
    for (int nt = 0; nt < 16; ++nt) {
        int n0 = nhalf + nt*16;
        const unsigned short* bp = W1t + (size_t)(n0 + lr)*128 + lg*8;
        f32x4 acc = {0.f, 0.f, 0.f, 0.f};
        #pragma unroll
        for (int ks = 0; ks < 4; ++ks)
            acc = __builtin_amdgcn_mfma_f32_16x16x32_bf16(a[ks],
                      *reinterpret_cast<const frag8*>(bp + ks*32), acc, 0, 0, 0);
        #pragma unroll
        for (int r = 0; r < 4; ++r) {
            int rowl = mrow + lg*4 + r;
            int col  = n0 + lr;
            float xv = acc[r] + bf1[col];
            H[rowl*LDH_M + col] = f2bf(0.5f*xv*(1.f + erff(xv*0.70710678118f)));
        }
    }
    __syncthreads();
    int n0b = (w & 1)*64;
    f32x4 acc2[4] = {};
    #pragma unroll
    for (int ks = 0; ks < 16; ++ks) {
        frag8 hf = *reinterpret_cast<const frag8*>(&H[(mrow + lr)*LDH_M + ks*32 + lg*8]);
        #pragma unroll
        for (int nt = 0; nt < 4; ++nt) {
            const unsigned short* bp = W2t + (size_t)(n0b + nt*16 + lr)*512 + ks*32 + lg*8;
            acc2[nt] = __builtin_amdgcn_mfma_f32_16x16x32_bf16(hf,
                           *reinterpret_cast<const frag8*>(bp), acc2[nt], 0, 0, 0);
        }
    }
    #pragma unroll
    for (int nt = 0; nt < 4; ++nt)
        #pragma unroll
        for (int r = 0; r < 4; ++r) {
            int rowl = mrow + lg*4 + r;
            int col  = n0b + nt*16 + lr;
            size_t off = (tok0 + rowl)*128 + col;
            t[off] += acc2[nt][r] + bf2[col];
        }
}

// ---------------------------------------------------------------- K7: NHWC -> NCHW transpose
__global__ __launch_bounds__(256) void k_transpose(
    const float* __restrict__ t, float* __restrict__ out)
{
    __shared__ float tile[128][33];
    int blk = blockIdx.x;                 // 8 * 128 * 4
    int ct = blk & 3;
    int h  = (blk >> 2) & 127;
    int b  = blk >> 9;
    const float* src = t + ((size_t)b*16384 + (size_t)h*128)*128 + ct*32;
    #pragma unroll
    for (int q = 0; q < 16; ++q) {
        int idx = threadIdx.x + q*256;
        int w = idx >> 5, c = idx & 31;
        tile[w][c] = src[(size_t)w*128 + c];
    }
    __syncthreads();
    float* dst = out + ((size_t)(b*128 + ct*32))*16384 + (size_t)h*128;
    #pragma unroll
    for (int q = 0; q < 16; ++q) {
        int idx = threadIdx.x + q*256;
        int c = idx >> 7, w = idx & 127;
        dst[(size_t)c*16384 + w] = tile[w][c];
    }
}

// ----------------------------------------------------------------
extern "C" void kernel_launch(void* const* d_in, const int* in_sizes, int n_in,
                              void* d_out, int out_size, void* d_ws, size_t ws_size,
                              hipStream_t stream)
{
    const float* x  = (const float*)d_in[0];
    const float* Wm = (const float*)d_in[1];
    const float* bm = (const float*)d_in[2];

    float* t            = (float*)d_ws;                               // T x 128 f32 (64 MB)
    unsigned short* qkv = (unsigned short*)(t + (size_t)Timg*128);    // T x 288 bf16 (72 MB)
    unsigned short* ao  = qkv + (size_t)Timg*288;                     // T x 96 bf16 (24 MB)
    unsigned short* wb  = ao + (size_t)Timg*96;                       // bf16 weights

    unsigned short* Wmt = wb;                    // [128][256]
    unsigned short* Wqt[2], *Wot[2], *W1t[2], *W2t[2];
    unsigned short* p = wb + 32768;
    for (int i = 0; i < 2; ++i) {
        Wqt[i] = p; p += 36864;   // [288][128]
        Wot[i] = p; p += 12288;   // [128][96]
        W1t[i] = p; p += 65536;   // [512][128]
        W2t[i] = p; p += 65536;   // [128][512]
    }

    k_wcvt<<<(256*128 + 255)/256, 256, 0, stream>>>(Wm, Wmt, 256, 128);
    for (int i = 0; i < 2; ++i) {
        k_wcvt<<<(128*288 + 255)/256, 256, 0, stream>>>((const float*)d_in[ 5 + i*12], Wqt[i], 128, 288);
        k_wcvt<<<( 96*128 + 255)/256, 256, 0, stream>>>((const float*)d_in[ 7 + i*12], Wot[i],  96, 128);
        k_wcvt<<<(128*512 + 255)/256, 256, 0, stream>>>((const float*)d_in[11 + i*12], W1t[i], 128, 512);
        k_wcvt<<<(512*128 + 255)/256, 256, 0, stream>>>((const float*)d_in[13 + i*12], W2t[i], 512, 128);
    }

    k_patchmerge<<<Timg/32, 256, 0, stream>>>(x, Wmt, bm, t);

    for (int blk = 0; blk < 2; ++blk) {
        const float* g1  = (const float*)d_in[ 3 + blk*12];
        const float* b1  = (const float*)d_in[ 4 + blk*12];
        const float* pos = (const float*)d_in[ 6 + blk*12];
        const float* bo  = (const float*)d_in[ 8 + blk*12];
        const float* g2  = (const float*)d_in[ 9 + blk*12];
        const float* b2  = (const float*)d_in[10 + blk*12];
        const float* bf1 = (const float*)d_in[12 + blk*12];
        const float* bf2 = (const float*)d_in[14 + blk*12];

        k_qkv<<<Timg/32, 256, 0, stream>>>(t, g1, b1, Wqt[blk], qkv);
        k_attn<<<8*3*256, 64, 0, stream>>>(qkv, pos, ao, blk);
        k_proj<<<Timg/32, 256, 0, stream>>>(ao, Wot[blk], bo, t);
        k_mlp<<<Timg/32, 256, 0, stream>>>(t, g2, b2, W1t[blk], bf1, W2t[blk], bf2);
    }

    k_transpose<<<8*128*4, 256, 0, stream>>>(t, (float*)d_out);
}

// Round 3
// 660.156 us; speedup vs baseline: 3.3384x; 1.5482x over previous
//
#include <hip/hip_runtime.h>
#include <math.h>

#define Timg 131072            // 8 * 128 * 128 tokens after merge
#define SCALE 0.17677669529663689f

typedef __attribute__((ext_vector_type(8))) short frag8;
typedef __attribute__((ext_vector_type(8))) unsigned short us8;
typedef __attribute__((ext_vector_type(4))) float f32x4;

__device__ inline float bf2f(unsigned short u) {
    union { unsigned int i; float f; } v; v.i = ((unsigned int)u) << 16; return v.f;
}
__device__ inline unsigned short f2bf(float f) {
    union { float f; unsigned int i; } v; v.f = f;
    unsigned int r = v.i + 0x7fff + ((v.i >> 16) & 1);
    return (unsigned short)(r >> 16);
}
__device__ inline unsigned int pk2(float lo, float hi) {
    return ((unsigned int)f2bf(hi) << 16) | (unsigned int)f2bf(lo);
}

// ---------------------------------------------------------------- weight convert+transpose: dst[c][r] = bf16(src[r][c])
__global__ __launch_bounds__(256) void k_wcvt(
    const float* __restrict__ src, unsigned short* __restrict__ dst, int R, int C)
{
    int idx = blockIdx.x * 256 + threadIdx.x;
    if (idx >= R * C) return;
    int r = idx / C, c = idx % C;
    dst[(size_t)c * R + r] = f2bf(src[idx]);
}

// ---------------------------------------------------------------- K1: patch merge + MFMA GEMM (K=256 -> N=128), BM=64
#define LDA_PM 264
__global__ __launch_bounds__(256) void k_patchmerge(
    const float* __restrict__ x, const unsigned short* __restrict__ Wmt,
    const float* __restrict__ bm, float* __restrict__ t)
{
    __shared__ unsigned short A[64 * LDA_PM];
    int blk = blockIdx.x;              // 2048 = 8b x 128h x 2 halves
    int b   = blk >> 8;
    int rem = blk & 255;
    int h   = rem >> 1;
    int w0  = (rem & 1) * 64;          // token col start
    int tid = threadIdx.x;
    {
        int row = tid >> 1, half = tid & 1;   // row = c*2+ki (128 rows)
        int c = row >> 1, ki = row & 1;
        const float* src = x + (((size_t)(b*64 + c))*256 + (size_t)(2*h + ki))*256 + 2*w0 + half*64;
        int base = c*4 + ki*2;                // k = c*4 + ki*2 + kj
        #pragma unroll
        for (int q = 0; q < 16; ++q) {
            float4 v = *reinterpret_cast<const float4*>(src + q*4);
            int tk0 = (half*64 + q*4) >> 1;
            *reinterpret_cast<unsigned int*>(&A[ tk0     * LDA_PM + base]) = pk2(v.x, v.y);
            *reinterpret_cast<unsigned int*>(&A[(tk0 + 1)* LDA_PM + base]) = pk2(v.z, v.w);
        }
    }
    __syncthreads();
    int lane = tid & 63, w = tid >> 6;
    int lr = lane & 15, lg = lane >> 4;
    size_t tok0 = (size_t)blk * 64;
    #pragma unroll
    for (int nt = 0; nt < 2; ++nt) {
        int n0 = (w*2 + nt) * 16;
        f32x4 acc[4] = {};
        #pragma unroll
        for (int ks = 0; ks < 8; ++ks) {
            frag8 bfr = *reinterpret_cast<const frag8*>(Wmt + (size_t)(n0 + lr)*256 + ks*32 + lg*8);
            #pragma unroll
            for (int m = 0; m < 4; ++m) {
                frag8 af = *reinterpret_cast<const frag8*>(&A[(m*16 + lr)*LDA_PM + ks*32 + lg*8]);
                acc[m] = __builtin_amdgcn_mfma_f32_16x16x32_bf16(af, bfr, acc[m], 0, 0, 0);
            }
        }
        #pragma unroll
        for (int m = 0; m < 4; ++m)
            #pragma unroll
            for (int r = 0; r < 4; ++r) {
                int rowl = m*16 + lg*4 + r;
                int col  = n0 + lr;
                t[(tok0 + rowl)*128 + col] = acc[m][r] + bm[col];
            }
    }
}

// ---------------------------------------------------------------- K2: fused LN1 + QKV GEMM (128 -> 288), BM=64, bf16 out
#define LDA_Q 136
__global__ __launch_bounds__(256) void k_qkv(
    const float* __restrict__ t, const float* __restrict__ g, const float* __restrict__ be,
    const unsigned short* __restrict__ Wqt, unsigned short* __restrict__ qkv)
{
    __shared__ unsigned short A[64 * LDA_Q];
    size_t tok0 = (size_t)blockIdx.x * 64;
    int tid = threadIdx.x, lane = tid & 63, w = tid >> 6;
    #pragma unroll
    for (int it = 0; it < 16; ++it) {
        int m = w*16 + it;
        const float* p = t + (tok0 + m)*128;
        float2 v = *reinterpret_cast<const float2*>(p + lane*2);
        float s = v.x + v.y;
        #pragma unroll
        for (int o = 32; o; o >>= 1) s += __shfl_xor(s, o);
        float mean = s * 0.0078125f;
        float d0 = v.x - mean, d1 = v.y - mean;
        float q = d0*d0 + d1*d1;
        #pragma unroll
        for (int o = 32; o; o >>= 1) q += __shfl_xor(q, o);
        float rs = rsqrtf(q * 0.0078125f + 1e-5f);
        *reinterpret_cast<unsigned int*>(&A[m*LDA_Q + lane*2]) =
            pk2(d0*rs*g[lane*2] + be[lane*2], d1*rs*g[lane*2+1] + be[lane*2+1]);
    }
    __syncthreads();
    int lr = lane & 15, lg = lane >> 4;
    for (int nt = w; nt < 18; nt += 4) {
        int n0 = nt*16;
        f32x4 acc[4] = {};
        #pragma unroll
        for (int ks = 0; ks < 4; ++ks) {
            frag8 bfr = *reinterpret_cast<const frag8*>(Wqt + (size_t)(n0 + lr)*128 + ks*32 + lg*8);
            #pragma unroll
            for (int m = 0; m < 4; ++m) {
                frag8 af = *reinterpret_cast<const frag8*>(&A[(m*16 + lr)*LDA_Q + ks*32 + lg*8]);
                acc[m] = __builtin_amdgcn_mfma_f32_16x16x32_bf16(af, bfr, acc[m], 0, 0, 0);
            }
        }
        #pragma unroll
        for (int m = 0; m < 4; ++m)
            #pragma unroll
            for (int r = 0; r < 4; ++r)
                qkv[(tok0 + m*16 + lg*4 + r)*288 + n0 + lr] = f2bf(acc[m][r]);
    }
}

// ---------------------------------------------------------------- K4: window attention, one wave per (b, head, window)
__global__ __launch_bounds__(64) void k_attn(
    const unsigned short* __restrict__ qkv, const float* __restrict__ pos,
    unsigned short* __restrict__ ao, int shifted)
{
    __shared__ float Ks[64][36];
    __shared__ float Vs[64][36];
    __shared__ float ps[240];
    int blk  = blockIdx.x;          // 8*3*256 = 6144
    int win  = blk & 255;
    int bh   = blk >> 8;
    int head = bh % 3, b = bh / 3;
    int wy = win >> 4, wx = win & 15;
    int lane = threadIdx.x;
    int ir = lane >> 3, ic = lane & 7;
    int hh = wy*8 + ir, ww = wx*8 + ic;
    if (shifted) { hh = (hh + 4) & 127; ww = (ww + 4) & 127; }
    size_t tok = ((size_t)(b*128 + hh))*128 + ww;
    const unsigned short* base = qkv + tok*288 + head*32;
    float qr[32];
    #pragma unroll
    for (int d8 = 0; d8 < 4; ++d8) {
        us8 qv = *reinterpret_cast<const us8*>(base + d8*8);
        us8 kv = *reinterpret_cast<const us8*>(base +  96 + d8*8);
        us8 vv = *reinterpret_cast<const us8*>(base + 192 + d8*8);
        #pragma unroll
        for (int j = 0; j < 8; ++j) {
            qr[d8*8 + j]       = bf2f(qv[j]) * SCALE;
            Ks[lane][d8*8 + j] = bf2f(kv[j]);
            Vs[lane][d8*8 + j] = bf2f(vv[j]);
        }
    }
    for (int idx = lane; idx < 225; idx += 64) ps[idx] = pos[idx];
    __syncthreads();

    bool mUL = (shifted != 0) && (wy == 15);
    bool mLR = (shifted != 0) && (wx == 15);
    bool ru = ir >= 4, rl = ic >= 4;
    int off = (7 - ir)*15 + (7 - ic);

    float s[64];
    float mx = -1e30f;
    #pragma unroll
    for (int j = 0; j < 64; ++j) {
        float acc = 0.f;
        #pragma unroll
        for (int d4 = 0; d4 < 8; ++d4) {
            float4 kv = *reinterpret_cast<const float4*>(&Ks[j][d4*4]);
            acc += qr[d4*4+0]*kv.x + qr[d4*4+1]*kv.y + qr[d4*4+2]*kv.z + qr[d4*4+3]*kv.w;
        }
        int jr = j >> 3, jc = j & 7;
        float val = acc + ps[off + jr*15 + jc];
        if ((mUL && ((jr>=4) != ru)) || (mLR && ((jc>=4) != rl))) val = -1e30f;
        s[j] = val;
        mx = fmaxf(mx, val);
    }
    float sum = 0.f;
    #pragma unroll
    for (int j = 0; j < 64; ++j) { float e = __expf(s[j] - mx); s[j] = e; sum += e; }
    float inv = 1.0f / sum;
    float o[32] = {};
    #pragma unroll
    for (int j = 0; j < 64; ++j) {
        float a = s[j] * inv;
        #pragma unroll
        for (int d4 = 0; d4 < 8; ++d4) {
            float4 vv = *reinterpret_cast<const float4*>(&Vs[j][d4*4]);
            o[d4*4+0] += a*vv.x; o[d4*4+1] += a*vv.y; o[d4*4+2] += a*vv.z; o[d4*4+3] += a*vv.w;
        }
    }
    unsigned short* dst = ao + tok*96 + head*32;
    #pragma unroll
    for (int d8 = 0; d8 < 4; ++d8) {
        us8 ov;
        #pragma unroll
        for (int j = 0; j < 8; ++j) ov[j] = f2bf(o[d8*8 + j]);
        *reinterpret_cast<us8*>(dst + d8*8) = ov;
    }
}

// ---------------------------------------------------------------- K5: proj GEMM (96 -> 128) + residual into t, BM=64
#define LDA_P 104
__global__ __launch_bounds__(256) void k_proj(
    const unsigned short* __restrict__ ao, const unsigned short* __restrict__ Wot,
    const float* __restrict__ bo, float* __restrict__ t)
{
    __shared__ unsigned short A[64 * LDA_P];
    size_t tok0 = (size_t)blockIdx.x * 64;
    int tid = threadIdx.x;
    #pragma unroll
    for (int q = 0; q < 3; ++q) {
        int idx = tid + q*256;
        int row = idx / 12, c8 = idx % 12;
        *reinterpret_cast<us8*>(&A[row*LDA_P + c8*8]) =
            *reinterpret_cast<const us8*>(ao + (tok0 + row)*96 + c8*8);
    }
    __syncthreads();
    int lane = tid & 63, w = tid >> 6;
    int lr = lane & 15, lg = lane >> 4;
    #pragma unroll
    for (int nt = 0; nt < 2; ++nt) {
        int n0 = (w*2 + nt)*16;
        f32x4 acc[4] = {};
        #pragma unroll
        for (int ks = 0; ks < 3; ++ks) {
            frag8 bfr = *reinterpret_cast<const frag8*>(Wot + (size_t)(n0 + lr)*96 + ks*32 + lg*8);
            #pragma unroll
            for (int m = 0; m < 4; ++m) {
                frag8 af = *reinterpret_cast<const frag8*>(&A[(m*16 + lr)*LDA_P + ks*32 + lg*8]);
                acc[m] = __builtin_amdgcn_mfma_f32_16x16x32_bf16(af, bfr, acc[m], 0, 0, 0);
            }
        }
        #pragma unroll
        for (int m = 0; m < 4; ++m)
            #pragma unroll
            for (int r = 0; r < 4; ++r) {
                int rowl = m*16 + lg*4 + r;
                int col  = n0 + lr;
                size_t off = (tok0 + rowl)*128 + col;
                t[off] += acc[m][r] + bo[col];
            }
    }
}

// ---------------------------------------------------------------- K6: fused LN2 + MLP (128->512 gelu ->128) + residual, BM=64, hidden chunked 4x128
#define LDA_M 136
__global__ __launch_bounds__(256) void k_mlp(
    float* __restrict__ t, const float* __restrict__ g, const float* __restrict__ be,
    const unsigned short* __restrict__ W1t, const float* __restrict__ bf1,
    const unsigned short* __restrict__ W2t, const float* __restrict__ bf2)
{
    __shared__ unsigned short A [64 * LDA_M];
    __shared__ unsigned short Hc[64 * LDA_M];
    size_t tok0 = (size_t)blockIdx.x * 64;
    int tid = threadIdx.x, lane = tid & 63, w = tid >> 6;
    #pragma unroll
    for (int it = 0; it < 16; ++it) {
        int m = w*16 + it;
        const float* p = t + (tok0 + m)*128;
        float2 v = *reinterpret_cast<const float2*>(p + lane*2);
        float s = v.x + v.y;
        #pragma unroll
        for (int o = 32; o; o >>= 1) s += __shfl_xor(s, o);
        float mean = s * 0.0078125f;
        float d0 = v.x - mean, d1 = v.y - mean;
        float q = d0*d0 + d1*d1;
        #pragma unroll
        for (int o = 32; o; o >>= 1) q += __shfl_xor(q, o);
        float rs = rsqrtf(q*0.0078125f + 1e-5f);
        *reinterpret_cast<unsigned int*>(&A[m*LDA_M + lane*2]) =
            pk2(d0*rs*g[lane*2] + be[lane*2], d1*rs*g[lane*2+1] + be[lane*2+1]);
    }
    __syncthreads();
    int lr = lane & 15, lg = lane >> 4;
    f32x4 acc2[2][4] = {};
    for (int kc = 0; kc < 4; ++kc) {
        f32x4 acc1[2][4] = {};
        #pragma unroll
        for (int nt = 0; nt < 2; ++nt) {
            int n0 = kc*128 + w*32 + nt*16;
            #pragma unroll
            for (int ks = 0; ks < 4; ++ks) {
                frag8 bfr = *reinterpret_cast<const frag8*>(W1t + (size_t)(n0 + lr)*128 + ks*32 + lg*8);
                #pragma unroll
                for (int m = 0; m < 4; ++m) {
                    frag8 af = *reinterpret_cast<const frag8*>(&A[(m*16 + lr)*LDA_M + ks*32 + lg*8]);
                    acc1[nt][m] = __builtin_amdgcn_mfma_f32_16x16x32_bf16(af, bfr, acc1[nt][m], 0, 0, 0);
                }
            }
        }
        __syncthreads();   // previous chunk's gemm2 done reading Hc
        #pragma unroll
        for (int nt = 0; nt < 2; ++nt)
            #pragma unroll
            for (int m = 0; m < 4; ++m)
                #pragma unroll
                for (int r = 0; r < 4; ++r) {
                    int rowl = m*16 + lg*4 + r;
                    int col  = w*32 + nt*16 + lr;
                    float xv = acc1[nt][m][r] + bf1[kc*128 + col];
                    Hc[rowl*LDA_M + col] = f2bf(0.5f*xv*(1.f + erff(xv*0.70710678118f)));
                }
        __syncthreads();
        #pragma unroll
        for (int nt = 0; nt < 2; ++nt) {
            int n0 = w*32 + nt*16;
            #pragma unroll
            for (int ks = 0; ks < 4; ++ks) {
                frag8 bfr = *reinterpret_cast<const frag8*>(W2t + (size_t)(n0 + lr)*512 + kc*128 + ks*32 + lg*8);
                #pragma unroll
                for (int m = 0; m < 4; ++m) {
                    frag8 hf = *reinterpret_cast<const frag8*>(&Hc[(m*16 + lr)*LDA_M + ks*32 + lg*8]);
                    acc2[nt][m] = __builtin_amdgcn_mfma_f32_16x16x32_bf16(hf, bfr, acc2[nt][m], 0, 0, 0);
                }
            }
        }
    }
    #pragma unroll
    for (int nt = 0; nt < 2; ++nt)
        #pragma unroll
        for (int m = 0; m < 4; ++m)
            #pragma unroll
            for (int r = 0; r < 4; ++r) {
                int rowl = m*16 + lg*4 + r;
                int col  = w*32 + nt*16 + lr;
                size_t off = (tok0 + rowl)*128 + col;
                t[off] += acc2[nt][m][r] + bf2[col];
            }
}

// ---------------------------------------------------------------- K7: NHWC -> NCHW transpose
__global__ __launch_bounds__(256) void k_transpose(
    const float* __restrict__ t, float* __restrict__ out)
{
    __shared__ float tile[128][33];
    int blk = blockIdx.x;                 // 8 * 128 * 4
    int ct = blk & 3;
    int h  = (blk >> 2) & 127;
    int b  = blk >> 9;
    const float* src = t + ((size_t)b*16384 + (size_t)h*128)*128 + ct*32;
    #pragma unroll
    for (int q = 0; q < 16; ++q) {
        int idx = threadIdx.x + q*256;
        int w = idx >> 5, c = idx & 31;
        tile[w][c] = src[(size_t)w*128 + c];
    }
    __syncthreads();
    float* dst = out + ((size_t)(b*128 + ct*32))*16384 + (size_t)h*128;
    #pragma unroll
    for (int q = 0; q < 16; ++q) {
        int idx = threadIdx.x + q*256;
        int c = idx >> 7, w = idx & 127;
        dst[(size_t)c*16384 + w] = tile[w][c];
    }
}

// ----------------------------------------------------------------
extern "C" void kernel_launch(void* const* d_in, const int* in_sizes, int n_in,
                              void* d_out, int out_size, void* d_ws, size_t ws_size,
                              hipStream_t stream)
{
    const float* x  = (const float*)d_in[0];
    const float* Wm = (const float*)d_in[1];
    const float* bm = (const float*)d_in[2];

    float* t            = (float*)d_ws;                               // T x 128 f32 (64 MB)
    unsigned short* qkv = (unsigned short*)(t + (size_t)Timg*128);    // T x 288 bf16 (72 MB)
    unsigned short* ao  = qkv + (size_t)Timg*288;                     // T x 96 bf16 (24 MB)
    unsigned short* wb  = ao + (size_t)Timg*96;                       // bf16 weights

    unsigned short* Wmt = wb;                    // [128][256]
    unsigned short* Wqt[2], *Wot[2], *W1t[2], *W2t[2];
    unsigned short* p = wb + 32768;
    for (int i = 0; i < 2; ++i) {
        Wqt[i] = p; p += 36864;   // [288][128]
        Wot[i] = p; p += 12288;   // [128][96]
        W1t[i] = p; p += 65536;   // [512][128]
        W2t[i] = p; p += 65536;   // [128][512]
    }

    k_wcvt<<<(256*128 + 255)/256, 256, 0, stream>>>(Wm, Wmt, 256, 128);
    for (int i = 0; i < 2; ++i) {
        k_wcvt<<<(128*288 + 255)/256, 256, 0, stream>>>((const float*)d_in[ 5 + i*12], Wqt[i], 128, 288);
        k_wcvt<<<( 96*128 + 255)/256, 256, 0, stream>>>((const float*)d_in[ 7 + i*12], Wot[i],  96, 128);
        k_wcvt<<<(128*512 + 255)/256, 256, 0, stream>>>((const float*)d_in[11 + i*12], W1t[i], 128, 512);
        k_wcvt<<<(512*128 + 255)/256, 256, 0, stream>>>((const float*)d_in[13 + i*12], W2t[i], 512, 128);
    }

    k_patchmerge<<<Timg/64, 256, 0, stream>>>(x, Wmt, bm, t);

    for (int blk = 0; blk < 2; ++blk) {
        const float* g1  = (const float*)d_in[ 3 + blk*12];
        const float* b1  = (const float*)d_in[ 4 + blk*12];
        const float* pos = (const float*)d_in[ 6 + blk*12];
        const float* bo  = (const float*)d_in[ 8 + blk*12];
        const float* g2  = (const float*)d_in[ 9 + blk*12];
        const float* b2  = (const float*)d_in[10 + blk*12];
        const float* bf1 = (const float*)d_in[12 + blk*12];
        const float* bf2 = (const float*)d_in[14 + blk*12];

        k_qkv<<<Timg/64, 256, 0, stream>>>(t, g1, b1, Wqt[blk], qkv);
        k_attn<<<8*3*256, 64, 0, stream>>>(qkv, pos, ao, blk);
        k_proj<<<Timg/64, 256, 0, stream>>>(ao, Wot[blk], bo, t);
        k_mlp<<<Timg/64, 256, 0, stream>>>(t, g2, b2, W1t[blk], bf1, W2t[blk], bf2);
    }

    k_transpose<<<8*128*4, 256, 0, stream>>>(t, (float*)d_out);
}

// Round 4
// 605.450 us; speedup vs baseline: 3.6401x; 1.0904x over previous
//
#include <hip/hip_runtime.h>
#include <math.h>

#define Timg 131072            // 8 * 128 * 128 tokens after merge
#define SCALE 0.17677669529663689f

typedef __attribute__((ext_vector_type(8))) short frag8;
typedef __attribute__((ext_vector_type(8))) unsigned short us8;
typedef __attribute__((ext_vector_type(4))) float f32x4;

__device__ inline float bf2f(unsigned short u) {
    union { unsigned int i; float f; } v; v.i = ((unsigned int)u) << 16; return v.f;
}
__device__ inline unsigned short f2bf(float f) {
    union { float f; unsigned int i; } v; v.f = f;
    unsigned int r = v.i + 0x7fff + ((v.i >> 16) & 1);
    return (unsigned short)(r >> 16);
}
__device__ inline unsigned int pk2(float lo, float hi) {
    return ((unsigned int)f2bf(hi) << 16) | (unsigned int)f2bf(lo);
}
__device__ inline float gelu_f(float x) {
    // tanh-form gelu as x * sigmoid(2z), z = 0.79788456*(x + 0.044715 x^3)
    float z2 = 1.5957691f * (x + 0.044715f * x * x * x);
    return x * __builtin_amdgcn_rcpf(1.f + __expf(-z2));
}

// ---------------------------------------------------------------- weight convert+transpose: dst[c][r] = bf16(src[r][c])
__global__ __launch_bounds__(256) void k_wcvt(
    const float* __restrict__ src, unsigned short* __restrict__ dst, int R, int C)
{
    int idx = blockIdx.x * 256 + threadIdx.x;
    if (idx >= R * C) return;
    int r = idx / C, c = idx % C;
    dst[(size_t)c * R + r] = f2bf(src[idx]);
}

// ---------------------------------------------------------------- K1: patch merge + MFMA GEMM (K=256 -> N=128), BM=64
#define LDA_PM 264
__global__ __launch_bounds__(256) void k_patchmerge(
    const float* __restrict__ x, const unsigned short* __restrict__ Wmt,
    const float* __restrict__ bm, float* __restrict__ t)
{
    __shared__ unsigned short A[64 * LDA_PM];
    int blk = blockIdx.x;              // 2048 = 8b x 128h x 2 halves
    int b   = blk >> 8;
    int rem = blk & 255;
    int h   = rem >> 1;
    int w0  = (rem & 1) * 64;          // token col start
    int tid = threadIdx.x;
    {
        int row = tid >> 1, half = tid & 1;   // row = c*2+ki (128 rows)
        int c = row >> 1, ki = row & 1;
        const float* src = x + (((size_t)(b*64 + c))*256 + (size_t)(2*h + ki))*256 + 2*w0 + half*64;
        int base = c*4 + ki*2;                // k = c*4 + ki*2 + kj
        #pragma unroll
        for (int q = 0; q < 16; ++q) {
            float4 v = *reinterpret_cast<const float4*>(src + q*4);
            int tk0 = (half*64 + q*4) >> 1;
            *reinterpret_cast<unsigned int*>(&A[ tk0     * LDA_PM + base]) = pk2(v.x, v.y);
            *reinterpret_cast<unsigned int*>(&A[(tk0 + 1)* LDA_PM + base]) = pk2(v.z, v.w);
        }
    }
    __syncthreads();
    int lane = tid & 63, w = tid >> 6;
    int lr = lane & 15, lg = lane >> 4;
    size_t tok0 = (size_t)blk * 64;
    #pragma unroll
    for (int nt = 0; nt < 2; ++nt) {
        int n0 = (w*2 + nt) * 16;
        f32x4 acc[4] = {};
        #pragma unroll
        for (int ks = 0; ks < 8; ++ks) {
            frag8 bfr = *reinterpret_cast<const frag8*>(Wmt + (size_t)(n0 + lr)*256 + ks*32 + lg*8);
            #pragma unroll
            for (int m = 0; m < 4; ++m) {
                frag8 af = *reinterpret_cast<const frag8*>(&A[(m*16 + lr)*LDA_PM + ks*32 + lg*8]);
                acc[m] = __builtin_amdgcn_mfma_f32_16x16x32_bf16(af, bfr, acc[m], 0, 0, 0);
            }
        }
        #pragma unroll
        for (int m = 0; m < 4; ++m)
            #pragma unroll
            for (int r = 0; r < 4; ++r) {
                int rowl = m*16 + lg*4 + r;
                int col  = n0 + lr;
                t[(tok0 + rowl)*128 + col] = acc[m][r] + bm[col];
            }
    }
}

// ---------------------------------------------------------------- K2: fused LN1 + QKV GEMM (128 -> 288), BM=64, bf16 out
#define LDA_Q 136
__global__ __launch_bounds__(256) void k_qkv(
    const float* __restrict__ t, const float* __restrict__ g, const float* __restrict__ be,
    const unsigned short* __restrict__ Wqt, unsigned short* __restrict__ qkv)
{
    __shared__ unsigned short A[64 * LDA_Q];
    size_t tok0 = (size_t)blockIdx.x * 64;
    int tid = threadIdx.x, lane = tid & 63, w = tid >> 6;
    #pragma unroll
    for (int it = 0; it < 16; ++it) {
        int m = w*16 + it;
        const float* p = t + (tok0 + m)*128;
        float2 v = *reinterpret_cast<const float2*>(p + lane*2);
        float s = v.x + v.y;
        #pragma unroll
        for (int o = 32; o; o >>= 1) s += __shfl_xor(s, o);
        float mean = s * 0.0078125f;
        float d0 = v.x - mean, d1 = v.y - mean;
        float q = d0*d0 + d1*d1;
        #pragma unroll
        for (int o = 32; o; o >>= 1) q += __shfl_xor(q, o);
        float rs = rsqrtf(q * 0.0078125f + 1e-5f);
        *reinterpret_cast<unsigned int*>(&A[m*LDA_Q + lane*2]) =
            pk2(d0*rs*g[lane*2] + be[lane*2], d1*rs*g[lane*2+1] + be[lane*2+1]);
    }
    __syncthreads();
    int lr = lane & 15, lg = lane >> 4;
    for (int nt = w; nt < 18; nt += 4) {
        int n0 = nt*16;
        f32x4 acc[4] = {};
        #pragma unroll
        for (int ks = 0; ks < 4; ++ks) {
            frag8 bfr = *reinterpret_cast<const frag8*>(Wqt + (size_t)(n0 + lr)*128 + ks*32 + lg*8);
            #pragma unroll
            for (int m = 0; m < 4; ++m) {
                frag8 af = *reinterpret_cast<const frag8*>(&A[(m*16 + lr)*LDA_Q + ks*32 + lg*8]);
                acc[m] = __builtin_amdgcn_mfma_f32_16x16x32_bf16(af, bfr, acc[m], 0, 0, 0);
            }
        }
        #pragma unroll
        for (int m = 0; m < 4; ++m)
            #pragma unroll
            for (int r = 0; r < 4; ++r)
                qkv[(tok0 + m*16 + lg*4 + r)*288 + n0 + lr] = f2bf(acc[m][r]);
    }
}

// ---------------------------------------------------------------- K4: window attention, one wave per (b, head, window)
__global__ __launch_bounds__(64) void k_attn(
    const unsigned short* __restrict__ qkv, const float* __restrict__ pos,
    unsigned short* __restrict__ ao, int shifted)
{
    __shared__ float Ks[64][36];
    __shared__ float Vs[64][36];
    __shared__ float ps[240];
    int blk  = blockIdx.x;          // 8*3*256 = 6144
    int win  = blk & 255;
    int bh   = blk >> 8;
    int head = bh % 3, b = bh / 3;
    int wy = win >> 4, wx = win & 15;
    int lane = threadIdx.x;
    int ir = lane >> 3, ic = lane & 7;
    int hh = wy*8 + ir, ww = wx*8 + ic;
    if (shifted) { hh = (hh + 4) & 127; ww = (ww + 4) & 127; }
    size_t tok = ((size_t)(b*128 + hh))*128 + ww;
    const unsigned short* base = qkv + tok*288 + head*32;
    float qr[32];
    #pragma unroll
    for (int d8 = 0; d8 < 4; ++d8) {
        us8 qv = *reinterpret_cast<const us8*>(base + d8*8);
        us8 kv = *reinterpret_cast<const us8*>(base +  96 + d8*8);
        us8 vv = *reinterpret_cast<const us8*>(base + 192 + d8*8);
        #pragma unroll
        for (int j = 0; j < 8; ++j) {
            qr[d8*8 + j]       = bf2f(qv[j]) * SCALE;
            Ks[lane][d8*8 + j] = bf2f(kv[j]);
            Vs[lane][d8*8 + j] = bf2f(vv[j]);
        }
    }
    for (int idx = lane; idx < 225; idx += 64) ps[idx] = pos[idx];
    __syncthreads();

    bool mUL = (shifted != 0) && (wy == 15);
    bool mLR = (shifted != 0) && (wx == 15);
    bool ru = ir >= 4, rl = ic >= 4;
    int off = (7 - ir)*15 + (7 - ic);

    float s[64];
    float mx = -1e30f;
    #pragma unroll
    for (int j = 0; j < 64; ++j) {
        float acc = 0.f;
        #pragma unroll
        for (int d4 = 0; d4 < 8; ++d4) {
            float4 kv = *reinterpret_cast<const float4*>(&Ks[j][d4*4]);
            acc += qr[d4*4+0]*kv.x + qr[d4*4+1]*kv.y + qr[d4*4+2]*kv.z + qr[d4*4+3]*kv.w;
        }
        int jr = j >> 3, jc = j & 7;
        float val = acc + ps[off + jr*15 + jc];
        if ((mUL && ((jr>=4) != ru)) || (mLR && ((jc>=4) != rl))) val = -1e30f;
        s[j] = val;
        mx = fmaxf(mx, val);
    }
    float sum = 0.f;
    #pragma unroll
    for (int j = 0; j < 64; ++j) { float e = __expf(s[j] - mx); s[j] = e; sum += e; }
    float inv = 1.0f / sum;
    float o[32] = {};
    #pragma unroll
    for (int j = 0; j < 64; ++j) {
        float a = s[j] * inv;
        #pragma unroll
        for (int d4 = 0; d4 < 8; ++d4) {
            float4 vv = *reinterpret_cast<const float4*>(&Vs[j][d4*4]);
            o[d4*4+0] += a*vv.x; o[d4*4+1] += a*vv.y; o[d4*4+2] += a*vv.z; o[d4*4+3] += a*vv.w;
        }
    }
    unsigned short* dst = ao + tok*96 + head*32;
    #pragma unroll
    for (int d8 = 0; d8 < 4; ++d8) {
        us8 ov;
        #pragma unroll
        for (int j = 0; j < 8; ++j) ov[j] = f2bf(o[d8*8 + j]);
        *reinterpret_cast<us8*>(dst + d8*8) = ov;
    }
}

// ---------------------------------------------------------------- K5: fused proj(96->128)+residual + LN2 + MLP(128->512 gelu ->128)+residual
#define LDA_M 136
__global__ __launch_bounds__(256) void k_pmlp(
    const unsigned short* __restrict__ ao, const unsigned short* __restrict__ Wot,
    const float* __restrict__ bo, float* __restrict__ t,
    const float* __restrict__ g, const float* __restrict__ be,
    const unsigned short* __restrict__ W1t, const float* __restrict__ bf1,
    const unsigned short* __restrict__ W2t, const float* __restrict__ bf2)
{
    __shared__ unsigned short A [64 * LDA_M];
    __shared__ unsigned short Hc[64 * LDA_M];
    __shared__ float stats[64][4][2];
    size_t tok0 = (size_t)blockIdx.x * 64;
    int tid = threadIdx.x, lane = tid & 63, w = tid >> 6;
    int lr = lane & 15, lg = lane >> 4;

    // ---- proj GEMM: acc[nt][m] over K=96, A-frags straight from global (L2-hot)
    f32x4 acc[2][4] = {};
    #pragma unroll
    for (int ks = 0; ks < 3; ++ks) {
        frag8 bf0 = *reinterpret_cast<const frag8*>(Wot + (size_t)(w*32      + lr)*96 + ks*32 + lg*8);
        frag8 bf1r= *reinterpret_cast<const frag8*>(Wot + (size_t)(w*32 + 16 + lr)*96 + ks*32 + lg*8);
        #pragma unroll
        for (int m = 0; m < 4; ++m) {
            frag8 af = *reinterpret_cast<const frag8*>(ao + (tok0 + m*16 + lr)*96 + ks*32 + lg*8);
            acc[0][m] = __builtin_amdgcn_mfma_f32_16x16x32_bf16(af, bf0,  acc[0][m], 0, 0, 0);
            acc[1][m] = __builtin_amdgcn_mfma_f32_16x16x32_bf16(af, bf1r, acc[1][m], 0, 0, 0);
        }
    }
    // ---- t1 = t + proj + bo  (register-resident residual stream)
    float t1[2][4][4];
    #pragma unroll
    for (int nt = 0; nt < 2; ++nt)
        #pragma unroll
        for (int m = 0; m < 4; ++m)
            #pragma unroll
            for (int r = 0; r < 4; ++r) {
                int rowl = m*16 + lg*4 + r;
                int col  = w*32 + nt*16 + lr;
                t1[nt][m][r] = t[(tok0 + rowl)*128 + col] + acc[nt][m][r] + bo[col];
            }
    // ---- LN2 stats: per-row partial sums over this wave's 32 cols
    #pragma unroll
    for (int m = 0; m < 4; ++m)
        #pragma unroll
        for (int r = 0; r < 4; ++r) {
            float v0 = t1[0][m][r], v1 = t1[1][m][r];
            float s = v0 + v1, q = v0*v0 + v1*v1;
            #pragma unroll
            for (int o = 8; o; o >>= 1) { s += __shfl_xor(s, o); q += __shfl_xor(q, o); }
            if (lr == 0) {
                int rowl = m*16 + lg*4 + r;
                stats[rowl][w][0] = s;
                stats[rowl][w][1] = q;
            }
        }
    __syncthreads();
    // ---- normalize in-register, write bf16 A tile
    #pragma unroll
    for (int m = 0; m < 4; ++m)
        #pragma unroll
        for (int r = 0; r < 4; ++r) {
            int rowl = m*16 + lg*4 + r;
            float s = 0.f, q = 0.f;
            #pragma unroll
            for (int ww2 = 0; ww2 < 4; ++ww2) { s += stats[rowl][ww2][0]; q += stats[rowl][ww2][1]; }
            float mean = s * 0.0078125f;
            float var  = fmaxf(q * 0.0078125f - mean*mean, 0.f);
            float rs   = rsqrtf(var + 1e-5f);
            #pragma unroll
            for (int nt = 0; nt < 2; ++nt) {
                int col = w*32 + nt*16 + lr;
                A[rowl*LDA_M + col] = f2bf((t1[nt][m][r] - mean)*rs*g[col] + be[col]);
            }
        }
    // ---- MLP: 4 hidden chunks of 128
    f32x4 acc2[2][4] = {};
    for (int kc = 0; kc < 4; ++kc) {
        __syncthreads();   // A ready (kc=0) / prev GEMM2 done reading Hc
        #pragma unroll
        for (int nt = 0; nt < 2; ++nt) {
            int n0 = kc*128 + w*32 + nt*16;
            f32x4 acc1[4] = {};
            #pragma unroll
            for (int ks = 0; ks < 4; ++ks) {
                frag8 bfr = *reinterpret_cast<const frag8*>(W1t + (size_t)(n0 + lr)*128 + ks*32 + lg*8);
                #pragma unroll
                for (int m = 0; m < 4; ++m) {
                    frag8 af = *reinterpret_cast<const frag8*>(&A[(m*16 + lr)*LDA_M + ks*32 + lg*8]);
                    acc1[m] = __builtin_amdgcn_mfma_f32_16x16x32_bf16(af, bfr, acc1[m], 0, 0, 0);
                }
            }
            #pragma unroll
            for (int m = 0; m < 4; ++m)
                #pragma unroll
                for (int r = 0; r < 4; ++r) {
                    int rowl = m*16 + lg*4 + r;
                    int col  = w*32 + nt*16 + lr;
                    float xv = acc1[m][r] + bf1[kc*128 + col];
                    Hc[rowl*LDA_M + col] = f2bf(gelu_f(xv));
                }
        }
        __syncthreads();
        #pragma unroll
        for (int nt = 0; nt < 2; ++nt) {
            int n0 = w*32 + nt*16;
            #pragma unroll
            for (int ks = 0; ks < 4; ++ks) {
                frag8 bfr = *reinterpret_cast<const frag8*>(W2t + (size_t)(n0 + lr)*512 + kc*128 + ks*32 + lg*8);
                #pragma unroll
                for (int m = 0; m < 4; ++m) {
                    frag8 hf = *reinterpret_cast<const frag8*>(&Hc[(m*16 + lr)*LDA_M + ks*32 + lg*8]);
                    acc2[nt][m] = __builtin_amdgcn_mfma_f32_16x16x32_bf16(hf, bfr, acc2[nt][m], 0, 0, 0);
                }
            }
        }
    }
    // ---- t2 = t1 + mlp + bf2
    #pragma unroll
    for (int nt = 0; nt < 2; ++nt)
        #pragma unroll
        for (int m = 0; m < 4; ++m)
            #pragma unroll
            for (int r = 0; r < 4; ++r) {
                int rowl = m*16 + lg*4 + r;
                int col  = w*32 + nt*16 + lr;
                t[(tok0 + rowl)*128 + col] = t1[nt][m][r] + acc2[nt][m][r] + bf2[col];
            }
}

// ---------------------------------------------------------------- K7: NHWC -> NCHW transpose
__global__ __launch_bounds__(256) void k_transpose(
    const float* __restrict__ t, float* __restrict__ out)
{
    __shared__ float tile[128][33];
    int blk = blockIdx.x;                 // 8 * 128 * 4
    int ct = blk & 3;
    int h  = (blk >> 2) & 127;
    int b  = blk >> 9;
    const float* src = t + ((size_t)b*16384 + (size_t)h*128)*128 + ct*32;
    #pragma unroll
    for (int q = 0; q < 16; ++q) {
        int idx = threadIdx.x + q*256;
        int w = idx >> 5, c = idx & 31;
        tile[w][c] = src[(size_t)w*128 + c];
    }
    __syncthreads();
    float* dst = out + ((size_t)(b*128 + ct*32))*16384 + (size_t)h*128;
    #pragma unroll
    for (int q = 0; q < 16; ++q) {
        int idx = threadIdx.x + q*256;
        int c = idx >> 7, w = idx & 127;
        dst[(size_t)c*16384 + w] = tile[w][c];
    }
}

// ----------------------------------------------------------------
extern "C" void kernel_launch(void* const* d_in, const int* in_sizes, int n_in,
                              void* d_out, int out_size, void* d_ws, size_t ws_size,
                              hipStream_t stream)
{
    const float* x  = (const float*)d_in[0];
    const float* Wm = (const float*)d_in[1];
    const float* bm = (const float*)d_in[2];

    float* t            = (float*)d_ws;                               // T x 128 f32 (64 MB)
    unsigned short* qkv = (unsigned short*)(t + (size_t)Timg*128);    // T x 288 bf16 (72 MB)
    unsigned short* ao  = qkv + (size_t)Timg*288;                     // T x 96 bf16 (24 MB)
    unsigned short* wb  = ao + (size_t)Timg*96;                       // bf16 weights

    unsigned short* Wmt = wb;                    // [128][256]
    unsigned short* Wqt[2], *Wot[2], *W1t[2], *W2t[2];
    unsigned short* p = wb + 32768;
    for (int i = 0; i < 2; ++i) {
        Wqt[i] = p; p += 36864;   // [288][128]
        Wot[i] = p; p += 12288;   // [128][96]
        W1t[i] = p; p += 65536;   // [512][128]
        W2t[i] = p; p += 65536;   // [128][512]
    }

    k_wcvt<<<(256*128 + 255)/256, 256, 0, stream>>>(Wm, Wmt, 256, 128);
    for (int i = 0; i < 2; ++i) {
        k_wcvt<<<(128*288 + 255)/256, 256, 0, stream>>>((const float*)d_in[ 5 + i*12], Wqt[i], 128, 288);
        k_wcvt<<<( 96*128 + 255)/256, 256, 0, stream>>>((const float*)d_in[ 7 + i*12], Wot[i],  96, 128);
        k_wcvt<<<(128*512 + 255)/256, 256, 0, stream>>>((const float*)d_in[11 + i*12], W1t[i], 128, 512);
        k_wcvt<<<(512*128 + 255)/256, 256, 0, stream>>>((const float*)d_in[13 + i*12], W2t[i], 512, 128);
    }

    k_patchmerge<<<Timg/64, 256, 0, stream>>>(x, Wmt, bm, t);

    for (int blk = 0; blk < 2; ++blk) {
        const float* g1  = (const float*)d_in[ 3 + blk*12];
        const float* b1  = (const float*)d_in[ 4 + blk*12];
        const float* pos = (const float*)d_in[ 6 + blk*12];
        const float* bo  = (const float*)d_in[ 8 + blk*12];
        const float* g2  = (const float*)d_in[ 9 + blk*12];
        const float* b2  = (const float*)d_in[10 + blk*12];
        const float* bf1 = (const float*)d_in[12 + blk*12];
        const float* bf2 = (const float*)d_in[14 + blk*12];

        k_qkv<<<Timg/64, 256, 0, stream>>>(t, g1, b1, Wqt[blk], qkv);
        k_attn<<<8*3*256, 64, 0, stream>>>(qkv, pos, ao, blk);
        k_pmlp<<<Timg/64, 256, 0, stream>>>(ao, Wot[blk], bo, t, g2, b2, W1t[blk], bf1, W2t[blk], bf2);
    }

    k_transpose<<<8*128*4, 256, 0, stream>>>(t, (float*)d_out);
}

// Round 5
// 421.725 us; speedup vs baseline: 5.2259x; 1.4357x over previous
//
#include <hip/hip_runtime.h>
#include <math.h>

#define Timg 131072            // 8 * 128 * 128 tokens after merge
#define SCALE 0.17677669529663689f

typedef __attribute__((ext_vector_type(8))) short frag8;
typedef __attribute__((ext_vector_type(8))) unsigned short us8;
typedef __attribute__((ext_vector_type(4))) float f32x4;

__device__ inline float bf2f(unsigned short u) {
    union { unsigned int i; float f; } v; v.i = ((unsigned int)u) << 16; return v.f;
}
__device__ inline unsigned short f2bf(float f) {
    union { float f; unsigned int i; } v; v.f = f;
    unsigned int r = v.i + 0x7fff + ((v.i >> 16) & 1);
    return (unsigned short)(r >> 16);
}
__device__ inline unsigned int pk2(float lo, float hi) {
    return ((unsigned int)f2bf(hi) << 16) | (unsigned int)f2bf(lo);
}
__device__ inline float gelu_f(float x) {
    float z2 = 1.5957691f * (x + 0.044715f * x * x * x);
    return x * __builtin_amdgcn_rcpf(1.f + __expf(-z2));
}

// ---------------------------------------------------------------- weight convert+transpose: dst[c][r] = bf16(src[r][c])
__global__ __launch_bounds__(256) void k_wcvt(
    const float* __restrict__ src, unsigned short* __restrict__ dst, int R, int C)
{
    int idx = blockIdx.x * 256 + threadIdx.x;
    if (idx >= R * C) return;
    int r = idx / C, c = idx % C;
    dst[(size_t)c * R + r] = f2bf(src[idx]);
}

// ---------------------------------------------------------------- K1: patch merge + MFMA GEMM (K=256 -> N=128), BM=64
#define LDA_PM 264
__global__ __launch_bounds__(256) void k_patchmerge(
    const float* __restrict__ x, const unsigned short* __restrict__ Wmt,
    const float* __restrict__ bm, float* __restrict__ t)
{
    __shared__ unsigned short A[64 * LDA_PM];
    int blk = blockIdx.x;              // 2048 = 8b x 128h x 2 halves
    int b   = blk >> 8;
    int rem = blk & 255;
    int h   = rem >> 1;
    int w0  = (rem & 1) * 64;
    int tid = threadIdx.x;
    {
        int row = tid >> 1, half = tid & 1;
        int c = row >> 1, ki = row & 1;
        const float* src = x + (((size_t)(b*64 + c))*256 + (size_t)(2*h + ki))*256 + 2*w0 + half*64;
        int base = c*4 + ki*2;
        #pragma unroll
        for (int q = 0; q < 16; ++q) {
            float4 v = *reinterpret_cast<const float4*>(src + q*4);
            int tk0 = (half*64 + q*4) >> 1;
            *reinterpret_cast<unsigned int*>(&A[ tk0     * LDA_PM + base]) = pk2(v.x, v.y);
            *reinterpret_cast<unsigned int*>(&A[(tk0 + 1)* LDA_PM + base]) = pk2(v.z, v.w);
        }
    }
    __syncthreads();
    int lane = tid & 63, w = tid >> 6;
    int lr = lane & 15, lg = lane >> 4;
    size_t tok0 = (size_t)blk * 64;
    #pragma unroll
    for (int nt = 0; nt < 2; ++nt) {
        int n0 = (w*2 + nt) * 16;
        f32x4 acc[4] = {};
        #pragma unroll
        for (int ks = 0; ks < 8; ++ks) {
            frag8 bfr = *reinterpret_cast<const frag8*>(Wmt + (size_t)(n0 + lr)*256 + ks*32 + lg*8);
            #pragma unroll
            for (int m = 0; m < 4; ++m) {
                frag8 af = *reinterpret_cast<const frag8*>(&A[(m*16 + lr)*LDA_PM + ks*32 + lg*8]);
                acc[m] = __builtin_amdgcn_mfma_f32_16x16x32_bf16(af, bfr, acc[m], 0, 0, 0);
            }
        }
        #pragma unroll
        for (int m = 0; m < 4; ++m)
            #pragma unroll
            for (int r = 0; r < 4; ++r) {
                int rowl = m*16 + lg*4 + r;
                int col  = n0 + lr;
                t[(tok0 + rowl)*128 + col] = acc[m][r] + bm[col];
            }
    }
}

// ---------------------------------------------------------------- K2: mega-kernel: one window (64 tokens) per block.
// LN1 -> QKV GEMM -> window attention (MFMA) -> proj + residual -> LN2 -> MLP -> residual
// LDS layout (bytes, all 16B-aligned; strides in bf16 elements, multiples of 8):
#define LDQK 200   // QK rows [64][200]: Q cols 0..95 (pre-scaled), K cols 96..191
#define LDVT 72    // Vt [96][72]  (V transposed: d-major)
#define LDP  72    // P  [64][72]  (softmax probs, wave-local rows)
#define LDAO 104   // ao [64][104] (attn out, 96 cols)
#define LDA  136   // A  [64][136] (LN1 out, then LN2 out)
#define LDH  136   // Hc [64][136] (MLP hidden chunk, overlays QK/Vt)
#define OFF_VT  25600                 // 64*200*2
#define R1SZ    39424                 // OFF_VT + 96*72*2
#define OFF_AO  48640                 // R1SZ + 64*72*2
#define SMEMSZ  61952                 // OFF_AO + 64*104*2
__global__ __launch_bounds__(256) void k_block(
    const float* __restrict__ pos, float* __restrict__ t,
    const float* __restrict__ g1, const float* __restrict__ b1,
    const unsigned short* __restrict__ Wqt,
    const unsigned short* __restrict__ Wot, const float* __restrict__ bo,
    const float* __restrict__ g2, const float* __restrict__ b2,
    const unsigned short* __restrict__ W1t, const float* __restrict__ bf1,
    const unsigned short* __restrict__ W2t, const float* __restrict__ bf2,
    int shifted)
{
    __shared__ __attribute__((aligned(16))) char smem[SMEMSZ];
    __shared__ float stats[64][4][2];
    __shared__ float ps[225];
    unsigned short* QK   = (unsigned short*)(smem);
    unsigned short* Vt   = (unsigned short*)(smem + OFF_VT);
    unsigned short* Hc   = (unsigned short*)(smem);            // after attn done
    unsigned short* Abuf = (unsigned short*)(smem + R1SZ);     // LN1 out, later LN2 out
    unsigned short* P    = (unsigned short*)(smem + R1SZ);     // after QKV done (A1 dead)
    unsigned short* ao   = (unsigned short*)(smem + OFF_AO);

    int blk = blockIdx.x;              // 2048 = 8b x 256 windows
    int b   = blk >> 8;
    int win = blk & 255;
    int wy  = win >> 4, wx = win & 15;
    int tid = threadIdx.x, lane = tid & 63, w = tid >> 6;
    int lr  = lane & 15, lg = lane >> 4;
    int sh  = shifted ? 4 : 0;

    for (int idx = tid; idx < 225; idx += 256) ps[idx] = pos[idx];

    // ---- Phase 1: LN1 over gathered window rows -> Abuf bf16
    #pragma unroll
    for (int it = 0; it < 16; ++it) {
        int m  = w*16 + it;
        int ir = m >> 3, ic = m & 7;
        int hh = (wy*8 + ir + sh) & 127, ww = (wx*8 + ic + sh) & 127;
        const float* p = t + ((size_t)((b*128 + hh)*128 + ww))*128;
        float2 v = *reinterpret_cast<const float2*>(p + lane*2);
        float s = v.x + v.y;
        #pragma unroll
        for (int o = 32; o; o >>= 1) s += __shfl_xor(s, o);
        float mean = s * 0.0078125f;
        float d0 = v.x - mean, d1 = v.y - mean;
        float q = d0*d0 + d1*d1;
        #pragma unroll
        for (int o = 32; o; o >>= 1) q += __shfl_xor(q, o);
        float rs = rsqrtf(q * 0.0078125f + 1e-5f);
        *reinterpret_cast<unsigned int*>(&Abuf[m*LDA + lane*2]) =
            pk2(d0*rs*g1[lane*2] + b1[lane*2], d1*rs*g1[lane*2+1] + b1[lane*2+1]);
    }
    __syncthreads();

    // ---- Phase 2: QKV GEMM (M=64, N=288, K=128): Q/K -> QK rows, V -> Vt transposed
    for (int nt = w; nt < 18; nt += 4) {
        f32x4 acc[4] = {};
        #pragma unroll
        for (int ks = 0; ks < 4; ++ks) {
            frag8 bfr = *reinterpret_cast<const frag8*>(Wqt + (size_t)(nt*16 + lr)*128 + ks*32 + lg*8);
            #pragma unroll
            for (int m = 0; m < 4; ++m) {
                frag8 af = *reinterpret_cast<const frag8*>(&Abuf[(m*16 + lr)*LDA + ks*32 + lg*8]);
                acc[m] = __builtin_amdgcn_mfma_f32_16x16x32_bf16(af, bfr, acc[m], 0, 0, 0);
            }
        }
        if (nt < 6) {            // Q (pre-scaled)
            #pragma unroll
            for (int m = 0; m < 4; ++m)
                #pragma unroll
                for (int r = 0; r < 4; ++r)
                    QK[(m*16 + lg*4 + r)*LDQK + nt*16 + lr] = f2bf(acc[m][r] * SCALE);
        } else if (nt < 12) {    // K at cols 96..191 (= nt*16 directly)
            #pragma unroll
            for (int m = 0; m < 4; ++m)
                #pragma unroll
                for (int r = 0; r < 4; ++r)
                    QK[(m*16 + lg*4 + r)*LDQK + nt*16 + lr] = f2bf(acc[m][r]);
        } else {                 // V transposed: Vt[d][token]
            #pragma unroll
            for (int m = 0; m < 4; ++m)
                #pragma unroll
                for (int r = 0; r < 4; ++r)
                    Vt[((nt - 12)*16 + lr)*LDVT + (m*16 + lg*4 + r)] = f2bf(acc[m][r]);
        }
    }
    __syncthreads();

    // ---- Phase 3: attention per head; wave w owns query rows w*16..w*16+15
    bool mUL = (shifted != 0) && (wy == 15);
    bool mLR = (shifted != 0) && (wx == 15);
    for (int h = 0; h < 3; ++h) {
        frag8 qf = *reinterpret_cast<const frag8*>(&QK[(w*16 + lr)*LDQK + h*32 + lg*8]);
        f32x4 s[4];
        #pragma unroll
        for (int jt = 0; jt < 4; ++jt) {
            frag8 kf = *reinterpret_cast<const frag8*>(&QK[(jt*16 + lr)*LDQK + 96 + h*32 + lg*8]);
            f32x4 z = {0.f, 0.f, 0.f, 0.f};
            s[jt] = __builtin_amdgcn_mfma_f32_16x16x32_bf16(qf, kf, z, 0, 0, 0);
        }
        #pragma unroll
        for (int r = 0; r < 4; ++r) {
            int i  = w*16 + lg*4 + r;
            int ir = i >> 3, ic = i & 7;
            int ro = (7 - ir)*15 + (7 - ic);
            float vals[4]; float mx = -1e30f;
            #pragma unroll
            for (int jt = 0; jt < 4; ++jt) {
                int j = jt*16 + lr, jr = j >> 3, jc = j & 7;
                float val = s[jt][r] + ps[ro + jr*15 + jc];
                if ((mUL && ((jr >= 4) != (ir >= 4))) || (mLR && ((jc >= 4) != (ic >= 4)))) val = -1e30f;
                vals[jt] = val; mx = fmaxf(mx, val);
            }
            #pragma unroll
            for (int o = 8; o; o >>= 1) mx = fmaxf(mx, __shfl_xor(mx, o));
            float sum = 0.f;
            #pragma unroll
            for (int jt = 0; jt < 4; ++jt) { vals[jt] = __expf(vals[jt] - mx); sum += vals[jt]; }
            #pragma unroll
            for (int o = 8; o; o >>= 1) sum += __shfl_xor(sum, o);
            float inv = __builtin_amdgcn_rcpf(sum);
            #pragma unroll
            for (int jt = 0; jt < 4; ++jt)
                P[i*LDP + jt*16 + lr] = f2bf(vals[jt] * inv);
        }
        __syncthreads();   // P rows are wave-local; barrier just orders LDS write->read
        #pragma unroll
        for (int nd = 0; nd < 2; ++nd) {
            f32x4 o4 = {0.f, 0.f, 0.f, 0.f};
            #pragma unroll
            for (int kt = 0; kt < 2; ++kt) {
                frag8 pf = *reinterpret_cast<const frag8*>(&P[(w*16 + lr)*LDP + kt*32 + lg*8]);
                frag8 vf = *reinterpret_cast<const frag8*>(&Vt[(h*32 + nd*16 + lr)*LDVT + kt*32 + lg*8]);
                o4 = __builtin_amdgcn_mfma_f32_16x16x32_bf16(pf, vf, o4, 0, 0, 0);
            }
            #pragma unroll
            for (int r = 0; r < 4; ++r)
                ao[(w*16 + lg*4 + r)*LDAO + h*32 + nd*16 + lr] = f2bf(o4[r]);
        }
        __syncthreads();   // before next head overwrites P
    }
    __syncthreads();       // ao complete (cross-wave reads next)

    // ---- Phase 4: proj (96->128) + residual t1 in registers
    f32x4 pacc[2][4] = {};
    #pragma unroll
    for (int ks = 0; ks < 3; ++ks) {
        frag8 bw0 = *reinterpret_cast<const frag8*>(Wot + (size_t)(w*32      + lr)*96 + ks*32 + lg*8);
        frag8 bw1 = *reinterpret_cast<const frag8*>(Wot + (size_t)(w*32 + 16 + lr)*96 + ks*32 + lg*8);
        #pragma unroll
        for (int m = 0; m < 4; ++m) {
            frag8 af = *reinterpret_cast<const frag8*>(&ao[(m*16 + lr)*LDAO + ks*32 + lg*8]);
            pacc[0][m] = __builtin_amdgcn_mfma_f32_16x16x32_bf16(af, bw0, pacc[0][m], 0, 0, 0);
            pacc[1][m] = __builtin_amdgcn_mfma_f32_16x16x32_bf16(af, bw1, pacc[1][m], 0, 0, 0);
        }
    }
    float t1[2][4][4];
    int   toks[4][4];
    #pragma unroll
    for (int m = 0; m < 4; ++m)
        #pragma unroll
        for (int r = 0; r < 4; ++r) {
            int rowl = m*16 + lg*4 + r;
            int ir = rowl >> 3, ic = rowl & 7;
            int hh = (wy*8 + ir + sh) & 127, ww = (wx*8 + ic + sh) & 127;
            toks[m][r] = (b*128 + hh)*128 + ww;
            #pragma unroll
            for (int nt = 0; nt < 2; ++nt) {
                int col = w*32 + nt*16 + lr;
                t1[nt][m][r] = t[(size_t)toks[m][r]*128 + col] + pacc[nt][m][r] + bo[col];
            }
        }
    // ---- LN2 stats
    #pragma unroll
    for (int m = 0; m < 4; ++m)
        #pragma unroll
        for (int r = 0; r < 4; ++r) {
            float v0 = t1[0][m][r], v1 = t1[1][m][r];
            float s = v0 + v1, q = v0*v0 + v1*v1;
            #pragma unroll
            for (int o = 8; o; o >>= 1) { s += __shfl_xor(s, o); q += __shfl_xor(q, o); }
            if (lr == 0) {
                int rowl = m*16 + lg*4 + r;
                stats[rowl][w][0] = s;
                stats[rowl][w][1] = q;
            }
        }
    __syncthreads();       // stats ready; also: all proj reads of ao done -> A2 may overwrite
    #pragma unroll
    for (int m = 0; m < 4; ++m)
        #pragma unroll
        for (int r = 0; r < 4; ++r) {
            int rowl = m*16 + lg*4 + r;
            float s = 0.f, q = 0.f;
            #pragma unroll
            for (int ww2 = 0; ww2 < 4; ++ww2) { s += stats[rowl][ww2][0]; q += stats[rowl][ww2][1]; }
            float mean = s * 0.0078125f;
            float var  = fmaxf(q * 0.0078125f - mean*mean, 0.f);
            float rs   = rsqrtf(var + 1e-5f);
            #pragma unroll
            for (int nt = 0; nt < 2; ++nt) {
                int col = w*32 + nt*16 + lr;
                Abuf[rowl*LDA + col] = f2bf((t1[nt][m][r] - mean)*rs*g2[col] + b2[col]);
            }
        }
    // ---- Phase 5: MLP, 4 hidden chunks of 128 (Hc overlays QK/Vt region)
    f32x4 acc2[2][4] = {};
    for (int kc = 0; kc < 4; ++kc) {
        __syncthreads();   // A2 ready (kc=0) / prev GEMM2 done reading Hc
        #pragma unroll
        for (int nt = 0; nt < 2; ++nt) {
            int n0 = kc*128 + w*32 + nt*16;
            f32x4 a1[4] = {};
            #pragma unroll
            for (int ks = 0; ks < 4; ++ks) {
                frag8 bfr = *reinterpret_cast<const frag8*>(W1t + (size_t)(n0 + lr)*128 + ks*32 + lg*8);
                #pragma unroll
                for (int m = 0; m < 4; ++m) {
                    frag8 af = *reinterpret_cast<const frag8*>(&Abuf[(m*16 + lr)*LDA + ks*32 + lg*8]);
                    a1[m] = __builtin_amdgcn_mfma_f32_16x16x32_bf16(af, bfr, a1[m], 0, 0, 0);
                }
            }
            #pragma unroll
            for (int m = 0; m < 4; ++m)
                #pragma unroll
                for (int r = 0; r < 4; ++r) {
                    int rowl = m*16 + lg*4 + r;
                    int col  = w*32 + nt*16 + lr;
                    float xv = a1[m][r] + bf1[kc*128 + col];
                    Hc[rowl*LDH + col] = f2bf(gelu_f(xv));
                }
        }
        __syncthreads();
        #pragma unroll
        for (int nt = 0; nt < 2; ++nt) {
            int n0 = w*32 + nt*16;
            #pragma unroll
            for (int ks = 0; ks < 4; ++ks) {
                frag8 bfr = *reinterpret_cast<const frag8*>(W2t + (size_t)(n0 + lr)*512 + kc*128 + ks*32 + lg*8);
                #pragma unroll
                for (int m = 0; m < 4; ++m) {
                    frag8 hf = *reinterpret_cast<const frag8*>(&Hc[(m*16 + lr)*LDH + ks*32 + lg*8]);
                    acc2[nt][m] = __builtin_amdgcn_mfma_f32_16x16x32_bf16(hf, bfr, acc2[nt][m], 0, 0, 0);
                }
            }
        }
    }
    // ---- t2 = t1 + mlp + bf2 (scatter to source coords)
    #pragma unroll
    for (int nt = 0; nt < 2; ++nt)
        #pragma unroll
        for (int m = 0; m < 4; ++m)
            #pragma unroll
            for (int r = 0; r < 4; ++r) {
                int col = w*32 + nt*16 + lr;
                t[(size_t)toks[m][r]*128 + col] = t1[nt][m][r] + acc2[nt][m][r] + bf2[col];
            }
}

// ---------------------------------------------------------------- K7: NHWC -> NCHW transpose
__global__ __launch_bounds__(256) void k_transpose(
    const float* __restrict__ t, float* __restrict__ out)
{
    __shared__ float tile[128][33];
    int blk = blockIdx.x;                 // 8 * 128 * 4
    int ct = blk & 3;
    int h  = (blk >> 2) & 127;
    int b  = blk >> 9;
    const float* src = t + ((size_t)b*16384 + (size_t)h*128)*128 + ct*32;
    #pragma unroll
    for (int q = 0; q < 16; ++q) {
        int idx = threadIdx.x + q*256;
        int w = idx >> 5, c = idx & 31;
        tile[w][c] = src[(size_t)w*128 + c];
    }
    __syncthreads();
    float* dst = out + ((size_t)(b*128 + ct*32))*16384 + (size_t)h*128;
    #pragma unroll
    for (int q = 0; q < 16; ++q) {
        int idx = threadIdx.x + q*256;
        int c = idx >> 7, w = idx & 127;
        dst[(size_t)c*16384 + w] = tile[w][c];
    }
}

// ----------------------------------------------------------------
extern "C" void kernel_launch(void* const* d_in, const int* in_sizes, int n_in,
                              void* d_out, int out_size, void* d_ws, size_t ws_size,
                              hipStream_t stream)
{
    const float* x  = (const float*)d_in[0];
    const float* Wm = (const float*)d_in[1];
    const float* bm = (const float*)d_in[2];

    float* t           = (float*)d_ws;                 // T x 128 f32 (64 MB)
    unsigned short* wb = (unsigned short*)(t + (size_t)Timg*128);

    unsigned short* Wmt = wb;                    // [128][256]
    unsigned short* Wqt[2], *Wot[2], *W1t[2], *W2t[2];
    unsigned short* p = wb + 32768;
    for (int i = 0; i < 2; ++i) {
        Wqt[i] = p; p += 36864;   // [288][128]
        Wot[i] = p; p += 12288;   // [128][96]
        W1t[i] = p; p += 65536;   // [512][128]
        W2t[i] = p; p += 65536;   // [128][512]
    }

    k_wcvt<<<(256*128 + 255)/256, 256, 0, stream>>>(Wm, Wmt, 256, 128);
    for (int i = 0; i < 2; ++i) {
        k_wcvt<<<(128*288 + 255)/256, 256, 0, stream>>>((const float*)d_in[ 5 + i*12], Wqt[i], 128, 288);
        k_wcvt<<<( 96*128 + 255)/256, 256, 0, stream>>>((const float*)d_in[ 7 + i*12], Wot[i],  96, 128);
        k_wcvt<<<(128*512 + 255)/256, 256, 0, stream>>>((const float*)d_in[11 + i*12], W1t[i], 128, 512);
        k_wcvt<<<(512*128 + 255)/256, 256, 0, stream>>>((const float*)d_in[13 + i*12], W2t[i], 512, 128);
    }

    k_patchmerge<<<Timg/64, 256, 0, stream>>>(x, Wmt, bm, t);

    for (int blk = 0; blk < 2; ++blk) {
        const float* g1  = (const float*)d_in[ 3 + blk*12];
        const float* b1  = (const float*)d_in[ 4 + blk*12];
        const float* pos = (const float*)d_in[ 6 + blk*12];
        const float* bo  = (const float*)d_in[ 8 + blk*12];
        const float* g2  = (const float*)d_in[ 9 + blk*12];
        const float* b2  = (const float*)d_in[10 + blk*12];
        const float* bf1 = (const float*)d_in[12 + blk*12];
        const float* bf2 = (const float*)d_in[14 + blk*12];

        k_block<<<2048, 256, 0, stream>>>(pos, t, g1, b1, Wqt[blk],
                                          Wot[blk], bo, g2, b2,
                                          W1t[blk], bf1, W2t[blk], bf2, blk);
    }

    k_transpose<<<8*128*4, 256, 0, stream>>>(t, (float*)d_out);
}